// Round 1
// baseline (423.649 us; speedup 1.0000x reference)
//
#include <hip/hip_runtime.h>
#include <hip/hip_bf16.h>

#define NN 50000
#define RR 16
#define H0 128
#define H1 64
#define EE 800000
#define NBASE 8

typedef __attribute__((ext_vector_type(8))) short short8;
typedef __attribute__((ext_vector_type(4))) float f32x4;

// ---------------- init ----------------
__global__ void k_init_out(float* __restrict__ out, const float* __restrict__ bias) {
    int i = blockIdx.x * blockDim.x + threadIdx.x;
    if (i < NN * H1) out[i] = bias[i & (H1 - 1)];
}

__global__ void k_zero_counts(float* __restrict__ counts) {
    int i = blockIdx.x * blockDim.x + threadIdx.x;
    if (i < RR * NN) counts[i] = 0.0f;
}

// ---------------- edge-norm counts ----------------
__global__ void k_count(const int* __restrict__ src, const int* __restrict__ rel,
                        float* __restrict__ counts) {
    int e = blockIdx.x * blockDim.x + threadIdx.x;
    if (e < EE) atomicAdd(&counts[rel[e] * NN + src[e]], 1.0f);
}

// ---------------- weights = comps @ bases, stored bf16 TRANSPOSED [r][o][k] ----------------
__global__ void k_weights(const float* __restrict__ comps, const float* __restrict__ bases,
                          __hip_bfloat16* __restrict__ wtT) {
    int idx = blockIdx.x * blockDim.x + threadIdx.x;
    if (idx >= RR * H1 * H0) return;
    int r = idx / (H1 * H0);
    int rem = idx % (H1 * H0);
    int o = rem / H0;
    int i = rem % H0;
    float acc = 0.0f;
#pragma unroll
    for (int b = 0; b < NBASE; ++b)
        acc += comps[r * NBASE + b] * bases[(b * H0 + i) * H1 + o];
    wtT[idx] = __float2bfloat16(acc);
}

// ---------------- nodes f32 -> bf16 ----------------
__global__ void k_convert_nodes(const float* __restrict__ nodes, __hip_bfloat16* __restrict__ nbf) {
    int i = blockIdx.x * blockDim.x + threadIdx.x;
    int base = i * 4;
    if (base < NN * H0) {
        float4 v = *(const float4*)&nodes[base];
        nbf[base + 0] = __float2bfloat16(v.x);
        nbf[base + 1] = __float2bfloat16(v.y);
        nbf[base + 2] = __float2bfloat16(v.z);
        nbf[base + 3] = __float2bfloat16(v.w);
    }
}

// ---------------- nw[r] = nodes @ W[r]  (MFMA bf16, one 16x16 tile per wave) ----------------
__global__ void k_gemm(const __hip_bfloat16* __restrict__ nbf,
                       const __hip_bfloat16* __restrict__ wtT,
                       __hip_bfloat16* __restrict__ nw) {
    int wid = blockIdx.x * (blockDim.x >> 6) + (threadIdx.x >> 6);
    int lane = threadIdx.x & 63;
    const int NT = NN / 16;           // 3125 node tiles
    int otile = wid & 3;              // 4 output tiles of 16
    int ntile = (wid >> 2) % NT;
    int r = wid / (4 * NT);
    if (r >= RR) return;

    int row = lane & 15;              // A row / B col / D col
    int kg  = lane >> 4;              // k-group (8 elems each)

    const __hip_bfloat16* aptr = &nbf[(size_t)(ntile * 16 + row) * H0 + kg * 8];
    const __hip_bfloat16* bptr = &wtT[((size_t)(r * H1 + otile * 16 + row)) * H0 + kg * 8];

    f32x4 acc = {0.f, 0.f, 0.f, 0.f};
#pragma unroll
    for (int kk = 0; kk < H0; kk += 32) {
        short8 a = *(const short8*)(aptr + kk);
        short8 b = *(const short8*)(bptr + kk);
        acc = __builtin_amdgcn_mfma_f32_16x16x32_bf16(a, b, acc, 0, 0, 0);
    }

    size_t base = ((size_t)r * NN + (size_t)ntile * 16) * H1 + otile * 16;
#pragma unroll
    for (int t = 0; t < 4; ++t) {
        int drow = kg * 4 + t;        // D: row=(lane>>4)*4+reg, col=lane&15
        nw[base + (size_t)drow * H1 + row] = __float2bfloat16(acc[t]);
    }
}

// ---------------- gather nw[rel,dst] * val, scatter-add to out[src] ----------------
__global__ void k_scatter(const int* __restrict__ src, const int* __restrict__ rel,
                          const int* __restrict__ dst, const float* __restrict__ counts,
                          const __hip_bfloat16* __restrict__ nw, float* __restrict__ out) {
    int e = blockIdx.x * (blockDim.x >> 6) + (threadIdx.x >> 6);
    int lane = threadIdx.x & 63;
    if (e >= EE) return;
    int s = src[e], r = rel[e], d = dst[e];
    float val = 1.0f / counts[r * NN + s];
    float m = __bfloat162float(nw[((size_t)r * NN + d) * H1 + lane]) * val;
    atomicAdd(&out[s * H1 + lane], m);
}

// ---------------- fallback: fused per-edge (if ws too small) ----------------
__global__ void k_fused_edge(const int* __restrict__ src, const int* __restrict__ rel,
                             const int* __restrict__ dst, const float* __restrict__ nodes,
                             const float* __restrict__ counts,
                             const __hip_bfloat16* __restrict__ wtT, float* __restrict__ out) {
    int e = blockIdx.x * (blockDim.x >> 6) + (threadIdx.x >> 6);
    int lane = threadIdx.x & 63;
    if (e >= EE) return;
    int s = src[e], r = rel[e], d = dst[e];
    float val = 1.0f / counts[r * NN + s];
    const __hip_bfloat16* w = &wtT[(size_t)(r * H1 + lane) * H0];
    const float* nd = &nodes[(size_t)d * H0];
    float acc = 0.0f;
#pragma unroll 8
    for (int i = 0; i < H0; ++i) acc += nd[i] * __bfloat162float(w[i]);
    atomicAdd(&out[s * H1 + lane], acc * val);
}

extern "C" void kernel_launch(void* const* d_in, const int* in_sizes, int n_in,
                              void* d_out, int out_size, void* d_ws, size_t ws_size,
                              hipStream_t stream) {
    const float* nodes = (const float*)d_in[0];
    const float* comps = (const float*)d_in[1];
    const float* bases = (const float*)d_in[2];
    const float* bias  = (const float*)d_in[3];
    const int*   src   = (const int*)d_in[4];
    const int*   rel   = (const int*)d_in[5];
    const int*   dst   = (const int*)d_in[6];
    float* out = (float*)d_out;

    char* ws = (char*)d_ws;
    // ws layout (bytes):
    //   counts  : RR*NN*4            = 3,200,000   @ 0
    //   nbf     : NN*H0*2            = 12,800,000  @ 3,200,000
    //   wtT     : RR*H1*H0*2         = 262,144     @ 16,000,000
    //   nw      : RR*NN*H1*2         = 102,400,000 @ 16,262,144
    float* counts        = (float*)ws;
    __hip_bfloat16* nbf  = (__hip_bfloat16*)(ws + 3200000);
    __hip_bfloat16* wtT  = (__hip_bfloat16*)(ws + 16000000);
    __hip_bfloat16* nw   = (__hip_bfloat16*)(ws + 16262144);
    const size_t need_full = 16262144ull + (size_t)RR * NN * H1 * 2ull;
    const size_t need_min  = 16262144ull;

    k_init_out<<<(NN * H1 + 255) / 256, 256, 0, stream>>>(out, bias);
    k_zero_counts<<<(RR * NN + 255) / 256, 256, 0, stream>>>(counts);
    k_count<<<(EE + 255) / 256, 256, 0, stream>>>(src, rel, counts);
    k_weights<<<(RR * H1 * H0 + 255) / 256, 256, 0, stream>>>(comps, bases, wtT);

    if (ws_size >= need_full) {
        k_convert_nodes<<<(NN * H0 / 4 + 255) / 256, 256, 0, stream>>>(nodes, nbf);
        k_gemm<<<RR * (NN / 16) * 4 / 4, 256, 0, stream>>>(nbf, wtT, nw);
        k_scatter<<<EE / 4, 256, 0, stream>>>(src, rel, dst, counts, nw, out);
    } else if (ws_size >= need_min) {
        k_fused_edge<<<EE / 4, 256, 0, stream>>>(src, rel, dst, nodes, counts, wtT, out);
    } else {
        // last-resort: assume at least counts+weights fit (3.5 MB)
        k_fused_edge<<<EE / 4, 256, 0, stream>>>(src, rel, dst, nodes, counts, wtT, out);
    }
}

// Round 2
// 313.049 us; speedup vs baseline: 1.3533x; 1.3533x over previous
//
#include <hip/hip_runtime.h>
#include <hip/hip_bf16.h>

#define NN 50000
#define RR 16
#define H0 128
#define H1 64
#define EE 800000
#define NBASE 8
#define NTILES (NN / 16)   // 3125

typedef __attribute__((ext_vector_type(8))) short short8;
typedef __attribute__((ext_vector_type(4))) float f32x4;

__device__ inline short f2bs(float x) {
    __hip_bfloat16 b = __float2bfloat16(x);
    return *reinterpret_cast<short*>(&b);
}

// ---------------- zero counts+tot+cursor (3.6 MB contiguous) ----------------
__global__ void k_zero(int* __restrict__ p, int n) {
    int i = blockIdx.x * blockDim.x + threadIdx.x;
    if (i < n) p[i] = 0;
}

// ---------------- per-edge histogram: counts[(r,s)] and tot[s] ----------------
__global__ void k_count(const int* __restrict__ src, const int* __restrict__ rel,
                        float* __restrict__ counts, int* __restrict__ tot) {
    int e = blockIdx.x * blockDim.x + threadIdx.x;
    if (e < EE) {
        int s = src[e];
        atomicAdd(&counts[rel[e] * NN + s], 1.0f);
        atomicAdd(&tot[s], 1);
    }
}

// ---------------- weights = comps @ bases, bf16 transposed [r][o][k] ----------------
__global__ void k_weights(const float* __restrict__ comps, const float* __restrict__ bases,
                          __hip_bfloat16* __restrict__ wtT) {
    int idx = blockIdx.x * blockDim.x + threadIdx.x;
    if (idx >= RR * H1 * H0) return;
    int r = idx / (H1 * H0);
    int rem = idx % (H1 * H0);
    int o = rem / H0;
    int i = rem % H0;
    float acc = 0.0f;
#pragma unroll
    for (int b = 0; b < NBASE; ++b)
        acc += comps[r * NBASE + b] * bases[(b * H0 + i) * H1 + o];
    wtT[idx] = __float2bfloat16(acc);
}

// ---------------- nw[r] = nodes @ W[r], A held in regs across all 16 r ----------------
// block = 4 waves, each wave owns a 16-node tile; fused f32->bf16 on A load;
// D transposed through wave-private LDS, stored as contiguous 1KB short8 rows.
__global__ void k_gemm2(const float* __restrict__ nodes,
                        const __hip_bfloat16* __restrict__ wtT,
                        __hip_bfloat16* __restrict__ nw) {
    __shared__ float sbuf[4][16][68];   // +4 pad breaks bank conflicts
    int wid = threadIdx.x >> 6;
    int lane = threadIdx.x & 63;
    int ntile = blockIdx.x * 4 + wid;
    if (ntile >= NTILES) return;       // no cross-wave sync used; safe
    int row = lane & 15;
    int kg  = lane >> 4;

    // A fragments: 4 k-steps x bf16x8, loaded once, reused for all 16 r
    short8 afrag[4];
    const float* ap = &nodes[(size_t)(ntile * 16 + row) * H0 + kg * 8];
#pragma unroll
    for (int ks = 0; ks < 4; ++ks) {
        float4 lo = *(const float4*)(ap + ks * 32);
        float4 hi = *(const float4*)(ap + ks * 32 + 4);
        short8 a;
        a[0] = f2bs(lo.x); a[1] = f2bs(lo.y); a[2] = f2bs(lo.z); a[3] = f2bs(lo.w);
        a[4] = f2bs(hi.x); a[5] = f2bs(hi.y); a[6] = f2bs(hi.z); a[7] = f2bs(hi.w);
        afrag[ks] = a;
    }

    for (int r = 0; r < RR; ++r) {
        const __hip_bfloat16* wr = &wtT[(size_t)r * H1 * H0];
#pragma unroll
        for (int ot = 0; ot < 4; ++ot) {
            f32x4 acc = {0.f, 0.f, 0.f, 0.f};
            const __hip_bfloat16* bp = wr + (size_t)(ot * 16 + row) * H0 + kg * 8;
#pragma unroll
            for (int ks = 0; ks < 4; ++ks)
                acc = __builtin_amdgcn_mfma_f32_16x16x32_bf16(
                    afrag[ks], *(const short8*)(bp + ks * 32), acc, 0, 0, 0);
#pragma unroll
            for (int t = 0; t < 4; ++t)
                sbuf[wid][kg * 4 + t][ot * 16 + row] = acc[t];   // D: row=kg*4+t, col=lane&15
        }
        // transpose out of LDS: each lane emits 8 consecutive bf16 (16B store)
#pragma unroll
        for (int it = 0; it < 2; ++it) {
            int lrow = (lane >> 3) + it * 8;
            int c8 = (lane & 7) * 8;
            const float* sp = &sbuf[wid][lrow][c8];
            short8 o;
#pragma unroll
            for (int j = 0; j < 8; ++j) o[j] = f2bs(sp[j]);
            *(short8*)&nw[((size_t)r * NN + (size_t)ntile * 16 + lrow) * H1 + c8] = o;
        }
    }
}

// ---------------- exclusive scan of tot[] (3 kernels) ----------------
__global__ void k_scan1(const int* __restrict__ tot, int* __restrict__ scanned,
                        int* __restrict__ bsums) {
    __shared__ int tmp[1024];
    int tid = threadIdx.x;
    int gid = blockIdx.x * 1024 + tid;
    int v = (gid < NN) ? tot[gid] : 0;
    tmp[tid] = v;
    __syncthreads();
    for (int off = 1; off < 1024; off <<= 1) {
        int t = (tid >= off) ? tmp[tid - off] : 0;
        __syncthreads();
        tmp[tid] += t;
        __syncthreads();
    }
    if (gid < NN) scanned[gid] = tmp[tid] - v;   // exclusive
    if (tid == 1023) bsums[blockIdx.x] = tmp[1023];
}

__global__ void k_scan2(const int* __restrict__ bsums, int* __restrict__ bsofs, int nb) {
    if (threadIdx.x == 0 && blockIdx.x == 0) {
        int running = 0;
        for (int i = 0; i < nb; ++i) { bsofs[i] = running; running += bsums[i]; }
    }
}

__global__ void k_scan3(const int* __restrict__ scanned, const int* __restrict__ bsofs,
                        int* __restrict__ base) {
    int i = blockIdx.x * blockDim.x + threadIdx.x;
    if (i < NN) base[i] = scanned[i] + bsofs[i >> 10];
}

// ---------------- bucket-place edges: recs[pos] = rel<<16 | dst ----------------
__global__ void k_place(const int* __restrict__ src, const int* __restrict__ rel,
                        const int* __restrict__ dst, const int* __restrict__ base,
                        int* __restrict__ cursor, unsigned* __restrict__ recs) {
    int e = blockIdx.x * blockDim.x + threadIdx.x;
    if (e < EE) {
        int s = src[e];
        int pos = base[s] + atomicAdd(&cursor[s], 1);
        recs[pos] = ((unsigned)rel[e] << 16) | (unsigned)dst[e];
    }
}

// ---------------- per-src accumulation: one wave per src, zero atomics ----------------
__global__ void k_accum(const int* __restrict__ tot, const int* __restrict__ base,
                        const unsigned* __restrict__ recs, const float* __restrict__ counts,
                        const __hip_bfloat16* __restrict__ nw, const float* __restrict__ bias,
                        float* __restrict__ out) {
    int s = blockIdx.x * 4 + (threadIdx.x >> 6);
    int lane = threadIdx.x & 63;
    if (s >= NN) return;
    int b0 = base[s], n = tot[s];
    float acc = bias[lane], acc2 = 0.0f;
    int i = 0;
    for (; i + 2 <= n; i += 2) {       // 2 independent gathers in flight
        unsigned rec0 = recs[b0 + i];
        unsigned rec1 = recs[b0 + i + 1];
        int r0 = rec0 >> 16, d0 = rec0 & 0xFFFF;
        int r1 = rec1 >> 16, d1 = rec1 & 0xFFFF;
        float v0 = 1.0f / counts[r0 * NN + s];
        float v1 = 1.0f / counts[r1 * NN + s];
        float m0 = __bfloat162float(nw[((size_t)r0 * NN + d0) * H1 + lane]);
        float m1 = __bfloat162float(nw[((size_t)r1 * NN + d1) * H1 + lane]);
        acc += v0 * m0;
        acc2 += v1 * m1;
    }
    if (i < n) {
        unsigned rec = recs[b0 + i];
        int r = rec >> 16, d = rec & 0xFFFF;
        acc += (1.0f / counts[r * NN + s]) *
               __bfloat162float(nw[((size_t)r * NN + d) * H1 + lane]);
    }
    out[(size_t)s * H1 + lane] = acc + acc2;
}

// ---------------- fallback (small ws): init + fused per-edge atomics ----------------
__global__ void k_init_out(float* __restrict__ out, const float* __restrict__ bias) {
    int i = blockIdx.x * blockDim.x + threadIdx.x;
    if (i < NN * H1) out[i] = bias[i & (H1 - 1)];
}

__global__ void k_count_only(const int* __restrict__ src, const int* __restrict__ rel,
                             float* __restrict__ counts) {
    int e = blockIdx.x * blockDim.x + threadIdx.x;
    if (e < EE) atomicAdd(&counts[rel[e] * NN + src[e]], 1.0f);
}

__global__ void k_fused_edge(const int* __restrict__ src, const int* __restrict__ rel,
                             const int* __restrict__ dst, const float* __restrict__ nodes,
                             const float* __restrict__ counts,
                             const __hip_bfloat16* __restrict__ wtT, float* __restrict__ out) {
    int e = blockIdx.x * (blockDim.x >> 6) + (threadIdx.x >> 6);
    int lane = threadIdx.x & 63;
    if (e >= EE) return;
    int s = src[e], r = rel[e], d = dst[e];
    float val = 1.0f / counts[r * NN + s];
    const __hip_bfloat16* w = &wtT[(size_t)(r * H1 + lane) * H0];
    const float* nd = &nodes[(size_t)d * H0];
    float acc = 0.0f;
#pragma unroll 8
    for (int i = 0; i < H0; ++i) acc += nd[i] * __bfloat162float(w[i]);
    atomicAdd(&out[s * H1 + lane], acc * val);
}

extern "C" void kernel_launch(void* const* d_in, const int* in_sizes, int n_in,
                              void* d_out, int out_size, void* d_ws, size_t ws_size,
                              hipStream_t stream) {
    const float* nodes = (const float*)d_in[0];
    const float* comps = (const float*)d_in[1];
    const float* bases = (const float*)d_in[2];
    const float* bias  = (const float*)d_in[3];
    const int*   src   = (const int*)d_in[4];
    const int*   rel   = (const int*)d_in[5];
    const int*   dst   = (const int*)d_in[6];
    float* out = (float*)d_out;

    char* ws = (char*)d_ws;
    // ws layout (bytes):
    //   counts  f32 [RR*NN]   @ 0          (3,200,000)
    //   tot     i32 [NN]      @ 3,200,000  (200,000)
    //   cursor  i32 [NN]      @ 3,400,000  (200,000)   <- zeroed together: 3.6 MB
    //   base    i32 [NN]      @ 3,600,000
    //   scanned i32 [NN]      @ 3,800,000
    //   bsums   i32 [64]      @ 4,000,000
    //   bsofs   i32 [64]      @ 4,000,256
    //   wtT     bf16 [R*H1*H0]@ 4,000,512  (262,144)
    //   recs    u32 [EE]      @ 4,262,656  (3,200,000)
    //   nw      bf16 [R*N*H1] @ 7,462,912  (102,400,000) -> total 109,862,912
    float* counts        = (float*)ws;
    int*   tot           = (int*)(ws + 3200000);
    int*   cursor        = (int*)(ws + 3400000);
    int*   basep         = (int*)(ws + 3600000);
    int*   scanned       = (int*)(ws + 3800000);
    int*   bsums         = (int*)(ws + 4000000);
    int*   bsofs         = (int*)(ws + 4000256);
    __hip_bfloat16* wtT  = (__hip_bfloat16*)(ws + 4000512);
    unsigned* recs       = (unsigned*)(ws + 4262656);
    __hip_bfloat16* nw   = (__hip_bfloat16*)(ws + 7462912);
    const size_t need_full = 7462912ull + (size_t)RR * NN * H1 * 2ull;

    if (ws_size >= need_full) {
        const int NB_SCAN = (NN + 1023) / 1024;   // 49
        k_zero<<<(900000 + 255) / 256, 256, 0, stream>>>((int*)ws, 900000);
        k_count<<<(EE + 255) / 256, 256, 0, stream>>>(src, rel, counts, tot);
        k_weights<<<(RR * H1 * H0 + 255) / 256, 256, 0, stream>>>(comps, bases, wtT);
        k_gemm2<<<(NTILES + 3) / 4, 256, 0, stream>>>(nodes, wtT, nw);
        k_scan1<<<NB_SCAN, 1024, 0, stream>>>(tot, scanned, bsums);
        k_scan2<<<1, 64, 0, stream>>>(bsums, bsofs, NB_SCAN);
        k_scan3<<<(NN + 255) / 256, 256, 0, stream>>>(scanned, bsofs, basep);
        k_place<<<(EE + 255) / 256, 256, 0, stream>>>(src, rel, dst, basep, cursor, recs);
        k_accum<<<(NN + 3) / 4, 256, 0, stream>>>(tot, basep, recs, counts, nw, bias, out);
    } else {
        // fallback: counts @0, wtT @3,200,000 (needs ~3.5 MB)
        __hip_bfloat16* wtT2 = (__hip_bfloat16*)(ws + 3200000);
        k_zero<<<(800000 + 255) / 256, 256, 0, stream>>>((int*)ws, 800000);
        k_count_only<<<(EE + 255) / 256, 256, 0, stream>>>(src, rel, counts);
        k_weights<<<(RR * H1 * H0 + 255) / 256, 256, 0, stream>>>(comps, bases, wtT2);
        k_init_out<<<(NN * H1 + 255) / 256, 256, 0, stream>>>(out, bias);
        k_fused_edge<<<EE / 4, 256, 0, stream>>>(src, rel, dst, nodes, counts, wtT2, out);
    }
}

// Round 3
// 249.401 us; speedup vs baseline: 1.6987x; 1.2552x over previous
//
#include <hip/hip_runtime.h>
#include <hip/hip_bf16.h>

#define NN 50000
#define RR 16
#define H0 128
#define H1 64
#define EE 800000
#define NBASE 8
#define NTILES (NN / 16)     // 3125
#define NGRPS ((NTILES + 3) / 4)   // 782 groups of 64 nodes

typedef __attribute__((ext_vector_type(8))) short short8;
typedef __attribute__((ext_vector_type(4))) short short4v;
typedef __attribute__((ext_vector_type(4))) float f32x4;

__device__ inline short f2bs(float x) {
    __hip_bfloat16 b = __float2bfloat16(x);
    return *reinterpret_cast<short*>(&b);
}

// ---------------- zero counts+tot+cursor (3.6 MB contiguous) ----------------
__global__ void k_zero(int* __restrict__ p, int n) {
    int i = blockIdx.x * blockDim.x + threadIdx.x;
    if (i < n) p[i] = 0;
}

// ---------------- per-edge histogram: counts[(r,s)] and tot[s] ----------------
__global__ void k_count(const int* __restrict__ src, const int* __restrict__ rel,
                        float* __restrict__ counts, int* __restrict__ tot) {
    int e = blockIdx.x * blockDim.x + threadIdx.x;
    if (e < EE) {
        int s = src[e];
        atomicAdd(&counts[rel[e] * NN + s], 1.0f);
        atomicAdd(&tot[s], 1);
    }
}

// ---------------- weights = comps @ bases, bf16 transposed [r][o][k] ----------------
__global__ void k_weights(const float* __restrict__ comps, const float* __restrict__ bases,
                          __hip_bfloat16* __restrict__ wtT) {
    int idx = blockIdx.x * blockDim.x + threadIdx.x;
    if (idx >= RR * H1 * H0) return;
    int r = idx / (H1 * H0);
    int rem = idx % (H1 * H0);
    int o = rem / H0;
    int i = rem % H0;
    float acc = 0.0f;
#pragma unroll
    for (int b = 0; b < NBASE; ++b)
        acc += comps[r * NBASE + b] * bases[(b * H0 + i) * H1 + o];
    wtT[idx] = __float2bfloat16(acc);
}

// ---------------- nw = nodes @ W[r], swapped-operand MFMA, no LDS ----------------
// 1 wave per block. Wave owns 64 nodes (4 A-tiles in regs) x 4 relations.
// D = Wt_tile(16ch x 32k) x node_tile(32k x 16n): lane holds 4 consecutive
// channels (row=kg*4+t) of one node (col=lane&15) -> direct 8B bf16 store.
__global__ void k_gemm3(const float* __restrict__ nodes,
                        const __hip_bfloat16* __restrict__ wtT,
                        __hip_bfloat16* __restrict__ nw) {
    int lane = threadIdx.x & 63;
    int ngrp = blockIdx.x >> 2;        // 64-node group
    int rg   = blockIdx.x & 3;         // relation group (4 rels)
    int n16  = lane & 15;              // node-in-tile / D col
    int kg   = lane >> 4;              // k-group (8 elems)

    int ntl = NTILES - ngrp * 4;       // active tiles in this group
    if (ntl > 4) ntl = 4;

    // A fragments: 4 tiles x 4 k-steps, f32->bf16 fused on load (64 VGPRs)
    short8 afrag[4][4];
#pragma unroll
    for (int t = 0; t < 4; ++t) {
        if (t < ntl) {
            const float* ap = &nodes[(size_t)((ngrp * 4 + t) * 16 + n16) * H0 + kg * 8];
#pragma unroll
            for (int ks = 0; ks < 4; ++ks) {
                float4 lo = *(const float4*)(ap + ks * 32);
                float4 hi = *(const float4*)(ap + ks * 32 + 4);
                short8 a;
                a[0] = f2bs(lo.x); a[1] = f2bs(lo.y); a[2] = f2bs(lo.z); a[3] = f2bs(lo.w);
                a[4] = f2bs(hi.x); a[5] = f2bs(hi.y); a[6] = f2bs(hi.z); a[7] = f2bs(hi.w);
                afrag[t][ks] = a;
            }
        }
    }

#pragma unroll
    for (int rr = 0; rr < 4; ++rr) {
        int r = rg * 4 + rr;
        const __hip_bfloat16* wr = &wtT[((size_t)(r * H1) + n16) * H0 + kg * 8];
#pragma unroll
        for (int ot = 0; ot < 4; ++ot) {
            f32x4 acc0 = {0,0,0,0}, acc1 = {0,0,0,0}, acc2 = {0,0,0,0}, acc3 = {0,0,0,0};
#pragma unroll
            for (int ks = 0; ks < 4; ++ks) {
                short8 w = *(const short8*)(wr + (size_t)(ot * 16) * H0 + ks * 32);
                acc0 = __builtin_amdgcn_mfma_f32_16x16x32_bf16(w, afrag[0][ks], acc0, 0, 0, 0);
                acc1 = __builtin_amdgcn_mfma_f32_16x16x32_bf16(w, afrag[1][ks], acc1, 0, 0, 0);
                acc2 = __builtin_amdgcn_mfma_f32_16x16x32_bf16(w, afrag[2][ks], acc2, 0, 0, 0);
                acc3 = __builtin_amdgcn_mfma_f32_16x16x32_bf16(w, afrag[3][ks], acc3, 0, 0, 0);
            }
            // store: node = ngrp*64 + t*16 + n16, channels ot*16 + kg*4 .. +3
#pragma unroll
            for (int t = 0; t < 4; ++t) {
                if (t >= ntl) break;
                f32x4 a = (t == 0) ? acc0 : (t == 1) ? acc1 : (t == 2) ? acc2 : acc3;
                short4v o;
                o[0] = f2bs(a[0]); o[1] = f2bs(a[1]); o[2] = f2bs(a[2]); o[3] = f2bs(a[3]);
                size_t node = (size_t)ngrp * 64 + t * 16 + n16;
                *(short4v*)&nw[((size_t)r * NN + node) * H1 + ot * 16 + kg * 4] = o;
            }
        }
    }
}

// ---------------- exclusive scan of tot[] (3 kernels) ----------------
__global__ void k_scan1(const int* __restrict__ tot, int* __restrict__ scanned,
                        int* __restrict__ bsums) {
    __shared__ int tmp[1024];
    int tid = threadIdx.x;
    int gid = blockIdx.x * 1024 + tid;
    int v = (gid < NN) ? tot[gid] : 0;
    tmp[tid] = v;
    __syncthreads();
    for (int off = 1; off < 1024; off <<= 1) {
        int t = (tid >= off) ? tmp[tid - off] : 0;
        __syncthreads();
        tmp[tid] += t;
        __syncthreads();
    }
    if (gid < NN) scanned[gid] = tmp[tid] - v;   // exclusive
    if (tid == 1023) bsums[blockIdx.x] = tmp[1023];
}

__global__ void k_scan2(const int* __restrict__ bsums, int* __restrict__ bsofs, int nb) {
    if (threadIdx.x == 0 && blockIdx.x == 0) {
        int running = 0;
        for (int i = 0; i < nb; ++i) { bsofs[i] = running; running += bsums[i]; }
    }
}

__global__ void k_scan3(const int* __restrict__ scanned, const int* __restrict__ bsofs,
                        int* __restrict__ base) {
    int i = blockIdx.x * blockDim.x + threadIdx.x;
    if (i < NN) base[i] = scanned[i] + bsofs[i >> 10];
}

// ---------------- bucket-place edges: recs[pos] = rel<<16 | dst ----------------
__global__ void k_place(const int* __restrict__ src, const int* __restrict__ rel,
                        const int* __restrict__ dst, const int* __restrict__ base,
                        int* __restrict__ cursor, unsigned* __restrict__ recs) {
    int e = blockIdx.x * blockDim.x + threadIdx.x;
    if (e < EE) {
        int s = src[e];
        int pos = base[s] + atomicAdd(&cursor[s], 1);
        recs[pos] = ((unsigned)rel[e] << 16) | (unsigned)dst[e];
    }
}

// ---------------- per-src accumulation: one wave per src, zero atomics ----------------
__global__ void k_accum(const int* __restrict__ tot, const int* __restrict__ base,
                        const unsigned* __restrict__ recs, const float* __restrict__ counts,
                        const __hip_bfloat16* __restrict__ nw, const float* __restrict__ bias,
                        float* __restrict__ out) {
    int s = blockIdx.x * 4 + (threadIdx.x >> 6);
    int lane = threadIdx.x & 63;
    if (s >= NN) return;
    int b0 = base[s], n = tot[s];
    float acc = bias[lane], acc2 = 0.0f;
    int i = 0;
    for (; i + 2 <= n; i += 2) {       // 2 independent gathers in flight
        unsigned rec0 = recs[b0 + i];
        unsigned rec1 = recs[b0 + i + 1];
        int r0 = rec0 >> 16, d0 = rec0 & 0xFFFF;
        int r1 = rec1 >> 16, d1 = rec1 & 0xFFFF;
        float v0 = 1.0f / counts[r0 * NN + s];
        float v1 = 1.0f / counts[r1 * NN + s];
        float m0 = __bfloat162float(nw[((size_t)r0 * NN + d0) * H1 + lane]);
        float m1 = __bfloat162float(nw[((size_t)r1 * NN + d1) * H1 + lane]);
        acc += v0 * m0;
        acc2 += v1 * m1;
    }
    if (i < n) {
        unsigned rec = recs[b0 + i];
        int r = rec >> 16, d = rec & 0xFFFF;
        acc += (1.0f / counts[r * NN + s]) *
               __bfloat162float(nw[((size_t)r * NN + d) * H1 + lane]);
    }
    out[(size_t)s * H1 + lane] = acc + acc2;
}

// ---------------- fallback (small ws): init + fused per-edge atomics ----------------
__global__ void k_init_out(float* __restrict__ out, const float* __restrict__ bias) {
    int i = blockIdx.x * blockDim.x + threadIdx.x;
    if (i < NN * H1) out[i] = bias[i & (H1 - 1)];
}

__global__ void k_count_only(const int* __restrict__ src, const int* __restrict__ rel,
                             float* __restrict__ counts) {
    int e = blockIdx.x * blockDim.x + threadIdx.x;
    if (e < EE) atomicAdd(&counts[rel[e] * NN + src[e]], 1.0f);
}

__global__ void k_fused_edge(const int* __restrict__ src, const int* __restrict__ rel,
                             const int* __restrict__ dst, const float* __restrict__ nodes,
                             const float* __restrict__ counts,
                             const __hip_bfloat16* __restrict__ wtT, float* __restrict__ out) {
    int e = blockIdx.x * (blockDim.x >> 6) + (threadIdx.x >> 6);
    int lane = threadIdx.x & 63;
    if (e >= EE) return;
    int s = src[e], r = rel[e], d = dst[e];
    float val = 1.0f / counts[r * NN + s];
    const __hip_bfloat16* w = &wtT[(size_t)(r * H1 + lane) * H0];
    const float* nd = &nodes[(size_t)d * H0];
    float acc = 0.0f;
#pragma unroll 8
    for (int i = 0; i < H0; ++i) acc += nd[i] * __bfloat162float(w[i]);
    atomicAdd(&out[s * H1 + lane], acc * val);
}

extern "C" void kernel_launch(void* const* d_in, const int* in_sizes, int n_in,
                              void* d_out, int out_size, void* d_ws, size_t ws_size,
                              hipStream_t stream) {
    const float* nodes = (const float*)d_in[0];
    const float* comps = (const float*)d_in[1];
    const float* bases = (const float*)d_in[2];
    const float* bias  = (const float*)d_in[3];
    const int*   src   = (const int*)d_in[4];
    const int*   rel   = (const int*)d_in[5];
    const int*   dst   = (const int*)d_in[6];
    float* out = (float*)d_out;

    char* ws = (char*)d_ws;
    float* counts        = (float*)ws;
    int*   tot           = (int*)(ws + 3200000);
    int*   cursor        = (int*)(ws + 3400000);
    int*   basep         = (int*)(ws + 3600000);
    int*   scanned       = (int*)(ws + 3800000);
    int*   bsums         = (int*)(ws + 4000000);
    int*   bsofs         = (int*)(ws + 4000256);
    __hip_bfloat16* wtT  = (__hip_bfloat16*)(ws + 4000512);
    unsigned* recs       = (unsigned*)(ws + 4262656);
    __hip_bfloat16* nw   = (__hip_bfloat16*)(ws + 7462912);
    const size_t need_full = 7462912ull + (size_t)RR * NN * H1 * 2ull;

    if (ws_size >= need_full) {
        const int NB_SCAN = (NN + 1023) / 1024;   // 49
        k_zero<<<(900000 + 255) / 256, 256, 0, stream>>>((int*)ws, 900000);
        k_count<<<(EE + 255) / 256, 256, 0, stream>>>(src, rel, counts, tot);
        k_weights<<<(RR * H1 * H0 + 255) / 256, 256, 0, stream>>>(comps, bases, wtT);
        k_gemm3<<<NGRPS * 4, 64, 0, stream>>>(nodes, wtT, nw);
        k_scan1<<<NB_SCAN, 1024, 0, stream>>>(tot, scanned, bsums);
        k_scan2<<<1, 64, 0, stream>>>(bsums, bsofs, NB_SCAN);
        k_scan3<<<(NN + 255) / 256, 256, 0, stream>>>(scanned, bsofs, basep);
        k_place<<<(EE + 255) / 256, 256, 0, stream>>>(src, rel, dst, basep, cursor, recs);
        k_accum<<<(NN + 3) / 4, 256, 0, stream>>>(tot, basep, recs, counts, nw, bias, out);
    } else {
        __hip_bfloat16* wtT2 = (__hip_bfloat16*)(ws + 3200000);
        k_zero<<<(800000 + 255) / 256, 256, 0, stream>>>((int*)ws, 800000);
        k_count_only<<<(EE + 255) / 256, 256, 0, stream>>>(src, rel, counts);
        k_weights<<<(RR * H1 * H0 + 255) / 256, 256, 0, stream>>>(comps, bases, wtT2);
        k_init_out<<<(NN * H1 + 255) / 256, 256, 0, stream>>>(out, bias);
        k_fused_edge<<<EE / 4, 256, 0, stream>>>(src, rel, dst, nodes, counts, wtT2, out);
    }
}

// Round 4
// 207.648 us; speedup vs baseline: 2.0402x; 1.2011x over previous
//
#include <hip/hip_runtime.h>
#include <hip/hip_bf16.h>

#define NN 50000
#define RR 16
#define H0 128
#define H1 64
#define EE 800000
#define NBASE 8
#define NTILES (NN / 16)            // 3125
#define NGRPS ((NTILES + 3) / 4)    // 782 groups of 64 nodes
#define GEMM_BLOCKS NGRPS           // 782 blocks x 4 waves = 3128 waves
#define COUNT_BLOCKS ((EE + 255) / 256)  // 3125
#define NM (NN * RR)                // 800000 bins

typedef __attribute__((ext_vector_type(8))) short short8;
typedef __attribute__((ext_vector_type(4))) short short4v;
typedef __attribute__((ext_vector_type(4))) float f32x4;

__device__ inline short f2bs(float x) {
    __hip_bfloat16 b = __float2bfloat16(x);
    return *reinterpret_cast<short*>(&b);
}

__global__ void k_zero(int* __restrict__ p, int n) {
    int i = blockIdx.x * blockDim.x + threadIdx.x;
    if (i < n) p[i] = 0;
}

// ---------------- weights = comps @ bases, bf16 transposed [r][o][k] ----------------
__global__ void k_weights(const float* __restrict__ comps, const float* __restrict__ bases,
                          __hip_bfloat16* __restrict__ wtT) {
    int idx = blockIdx.x * blockDim.x + threadIdx.x;
    if (idx >= RR * H1 * H0) return;
    int r = idx / (H1 * H0);
    int rem = idx % (H1 * H0);
    int o = rem / H0;
    int i = rem % H0;
    float acc = 0.0f;
#pragma unroll
    for (int b = 0; b < NBASE; ++b)
        acc += comps[r * NBASE + b] * bases[(b * H0 + i) * H1 + o];
    wtT[idx] = __float2bfloat16(acc);
}

// ---------------- fused: [gemm blocks] + [count blocks] ----------------
// gemm: wave owns 64 nodes x 4 relations, swapped-operand MFMA, direct 8B stores.
// count: int histogram over s-major bins cnt[s*16+r] (single atomic stream,
//        latency hidden under the concurrent MFMA blocks).
__global__ void k_fused(const float* __restrict__ nodes,
                        const __hip_bfloat16* __restrict__ wtT,
                        __hip_bfloat16* __restrict__ nw,
                        const int* __restrict__ src, const int* __restrict__ rel,
                        int* __restrict__ cnt) {
    if (blockIdx.x < GEMM_BLOCKS) {
        int wid = blockIdx.x * 4 + (threadIdx.x >> 6);
        int lane = threadIdx.x & 63;
        int ngrp = wid >> 2;
        int rg   = wid & 3;
        int n16  = lane & 15;
        int kg   = lane >> 4;

        int ntl = NTILES - ngrp * 4;
        if (ntl > 4) ntl = 4;

        short8 afrag[4][4];
#pragma unroll
        for (int t = 0; t < 4; ++t) {
            if (t < ntl) {
                const float* ap = &nodes[(size_t)((ngrp * 4 + t) * 16 + n16) * H0 + kg * 8];
#pragma unroll
                for (int ks = 0; ks < 4; ++ks) {
                    float4 lo = *(const float4*)(ap + ks * 32);
                    float4 hi = *(const float4*)(ap + ks * 32 + 4);
                    short8 a;
                    a[0] = f2bs(lo.x); a[1] = f2bs(lo.y); a[2] = f2bs(lo.z); a[3] = f2bs(lo.w);
                    a[4] = f2bs(hi.x); a[5] = f2bs(hi.y); a[6] = f2bs(hi.z); a[7] = f2bs(hi.w);
                    afrag[t][ks] = a;
                }
            }
        }

#pragma unroll
        for (int rr = 0; rr < 4; ++rr) {
            int r = rg * 4 + rr;
            const __hip_bfloat16* wr = &wtT[((size_t)(r * H1) + n16) * H0 + kg * 8];
#pragma unroll
            for (int ot = 0; ot < 4; ++ot) {
                f32x4 acc0 = {0,0,0,0}, acc1 = {0,0,0,0}, acc2 = {0,0,0,0}, acc3 = {0,0,0,0};
#pragma unroll
                for (int ks = 0; ks < 4; ++ks) {
                    short8 w = *(const short8*)(wr + (size_t)(ot * 16) * H0 + ks * 32);
                    acc0 = __builtin_amdgcn_mfma_f32_16x16x32_bf16(w, afrag[0][ks], acc0, 0, 0, 0);
                    acc1 = __builtin_amdgcn_mfma_f32_16x16x32_bf16(w, afrag[1][ks], acc1, 0, 0, 0);
                    acc2 = __builtin_amdgcn_mfma_f32_16x16x32_bf16(w, afrag[2][ks], acc2, 0, 0, 0);
                    acc3 = __builtin_amdgcn_mfma_f32_16x16x32_bf16(w, afrag[3][ks], acc3, 0, 0, 0);
                }
#pragma unroll
                for (int t = 0; t < 4; ++t) {
                    if (t >= ntl) break;
                    f32x4 a = (t == 0) ? acc0 : (t == 1) ? acc1 : (t == 2) ? acc2 : acc3;
                    short4v o;
                    o[0] = f2bs(a[0]); o[1] = f2bs(a[1]); o[2] = f2bs(a[2]); o[3] = f2bs(a[3]);
                    size_t node = (size_t)ngrp * 64 + t * 16 + n16;
                    *(short4v*)&nw[((size_t)r * NN + node) * H1 + ot * 16 + kg * 4] = o;
                }
            }
        }
    } else {
        int e = (blockIdx.x - GEMM_BLOCKS) * 256 + threadIdx.x;
        if (e < EE) atomicAdd(&cnt[src[e] * RR + rel[e]], 1);
    }
}

// ---------------- 3-level exclusive scan over cnt[NM] -> base2 ----------------
__global__ void k_scan1(const int* __restrict__ cnt, int* __restrict__ base2,
                        int* __restrict__ bsums) {
    __shared__ int tmp[1024];
    int tid = threadIdx.x;
    int gid = blockIdx.x * 1024 + tid;
    int v = (gid < NM) ? cnt[gid] : 0;
    tmp[tid] = v;
    __syncthreads();
    for (int off = 1; off < 1024; off <<= 1) {
        int t = (tid >= off) ? tmp[tid - off] : 0;
        __syncthreads();
        tmp[tid] += t;
        __syncthreads();
    }
    if (gid < NM) base2[gid] = tmp[tid] - v;   // exclusive
    if (tid == 1023) bsums[blockIdx.x] = tmp[1023];
}

__global__ void k_scan2(const int* __restrict__ bsums, int* __restrict__ bsofs, int nb) {
    __shared__ int tmp[1024];
    int tid = threadIdx.x;
    int v = (tid < nb) ? bsums[tid] : 0;
    tmp[tid] = v;
    __syncthreads();
    for (int off = 1; off < 1024; off <<= 1) {
        int t = (tid >= off) ? tmp[tid - off] : 0;
        __syncthreads();
        tmp[tid] += t;
        __syncthreads();
    }
    if (tid < nb) bsofs[tid] = tmp[tid] - v;   // exclusive block offsets
}

__global__ void k_scan3(int* __restrict__ base2, const int* __restrict__ bsofs) {
    int i = blockIdx.x * blockDim.x + threadIdx.x;
    if (i < NM) base2[i] += bsofs[i >> 10];
    if (i == 0) base2[NM] = EE;
}

// ---------------- bucket-place edges; cnt reused as down-cursor ----------------
__global__ void k_place(const int* __restrict__ src, const int* __restrict__ rel,
                        const int* __restrict__ dst, const int* __restrict__ base2,
                        int* __restrict__ cnt, unsigned* __restrict__ recs) {
    int e = blockIdx.x * blockDim.x + threadIdx.x;
    if (e < EE) {
        int s = src[e], r = rel[e];
        int bin = s * RR + r;
        int old = atomicAdd(&cnt[bin], -1);          // old in [1..count]
        int pos = base2[bin] + old - 1;
        recs[pos] = ((unsigned)r << 16) | (unsigned)dst[e];
    }
}

// ---------------- per-src accumulation: one wave per src, zero atomics ----------------
__global__ void k_accum(const int* __restrict__ base2, const unsigned* __restrict__ recs,
                        const __hip_bfloat16* __restrict__ nw, const float* __restrict__ bias,
                        float* __restrict__ out) {
    int s = blockIdx.x * 4 + (threadIdx.x >> 6);
    int lane = threadIdx.x & 63;
    if (s >= NN) return;
    int b0 = base2[s * RR];
    int n  = base2[s * RR + RR] - b0;
    const int* bnd = &base2[s * RR];
    float acc = bias[lane], acc2 = 0.0f;
    int i = 0;
    for (; i + 2 <= n; i += 2) {
        unsigned rec0 = recs[b0 + i];
        unsigned rec1 = recs[b0 + i + 1];
        int r0 = rec0 >> 16, d0 = rec0 & 0xFFFF;
        int r1 = rec1 >> 16, d1 = rec1 & 0xFFFF;
        float v0 = 1.0f / (float)(bnd[r0 + 1] - bnd[r0]);
        float v1 = 1.0f / (float)(bnd[r1 + 1] - bnd[r1]);
        float m0 = __bfloat162float(nw[((size_t)r0 * NN + d0) * H1 + lane]);
        float m1 = __bfloat162float(nw[((size_t)r1 * NN + d1) * H1 + lane]);
        acc += v0 * m0;
        acc2 += v1 * m1;
    }
    if (i < n) {
        unsigned rec = recs[b0 + i];
        int r = rec >> 16, d = rec & 0xFFFF;
        acc += (1.0f / (float)(bnd[r + 1] - bnd[r])) *
               __bfloat162float(nw[((size_t)r * NN + d) * H1 + lane]);
    }
    out[(size_t)s * H1 + lane] = acc + acc2;
}

// ---------------- fallback (small ws): init + fused per-edge atomics ----------------
__global__ void k_init_out(float* __restrict__ out, const float* __restrict__ bias) {
    int i = blockIdx.x * blockDim.x + threadIdx.x;
    if (i < NN * H1) out[i] = bias[i & (H1 - 1)];
}

__global__ void k_count_only(const int* __restrict__ src, const int* __restrict__ rel,
                             float* __restrict__ counts) {
    int e = blockIdx.x * blockDim.x + threadIdx.x;
    if (e < EE) atomicAdd(&counts[rel[e] * NN + src[e]], 1.0f);
}

__global__ void k_fused_edge(const int* __restrict__ src, const int* __restrict__ rel,
                             const int* __restrict__ dst, const float* __restrict__ nodes,
                             const float* __restrict__ counts,
                             const __hip_bfloat16* __restrict__ wtT, float* __restrict__ out) {
    int e = blockIdx.x * (blockDim.x >> 6) + (threadIdx.x >> 6);
    int lane = threadIdx.x & 63;
    if (e >= EE) return;
    int s = src[e], r = rel[e], d = dst[e];
    float val = 1.0f / counts[r * NN + s];
    const __hip_bfloat16* w = &wtT[(size_t)(r * H1 + lane) * H0];
    const float* nd = &nodes[(size_t)d * H0];
    float acc = 0.0f;
#pragma unroll 8
    for (int i = 0; i < H0; ++i) acc += nd[i] * __bfloat162float(w[i]);
    atomicAdd(&out[s * H1 + lane], acc * val);
}

extern "C" void kernel_launch(void* const* d_in, const int* in_sizes, int n_in,
                              void* d_out, int out_size, void* d_ws, size_t ws_size,
                              hipStream_t stream) {
    const float* nodes = (const float*)d_in[0];
    const float* comps = (const float*)d_in[1];
    const float* bases = (const float*)d_in[2];
    const float* bias  = (const float*)d_in[3];
    const int*   src   = (const int*)d_in[4];
    const int*   rel   = (const int*)d_in[5];
    const int*   dst   = (const int*)d_in[6];
    float* out = (float*)d_out;

    char* ws = (char*)d_ws;
    // ws layout (bytes):
    //   cnt    i32 [NM]       @ 0           (3,200,000)
    //   base2  i32 [NM+1]     @ 3,200,000   (3,200,016)
    //   bsums  i32 [800]      @ 6,400,016   (3,200)
    //   bsofs  i32 [800]      @ 6,403,216   (3,200)
    //   wtT    bf16 [R*H1*H0] @ 6,406,416   (262,144)
    //   recs   u32 [EE]       @ 6,668,560   (3,200,000)
    //   nw     bf16 [R*N*H1]  @ 9,868,560   (102,400,000)  -> total 112,268,560
    int*   cnt           = (int*)ws;
    int*   base2         = (int*)(ws + 3200000);
    int*   bsums         = (int*)(ws + 6400016);
    int*   bsofs         = (int*)(ws + 6403216);
    __hip_bfloat16* wtT  = (__hip_bfloat16*)(ws + 6406416);
    unsigned* recs       = (unsigned*)(ws + 6668560);
    __hip_bfloat16* nw   = (__hip_bfloat16*)(ws + 9868560);
    const size_t need_full = 9868560ull + (size_t)RR * NN * H1 * 2ull;

    if (ws_size >= need_full) {
        const int NB_SCAN = (NM + 1023) / 1024;   // 782
        k_zero<<<(NM + 255) / 256, 256, 0, stream>>>(cnt, NM);
        k_weights<<<(RR * H1 * H0 + 255) / 256, 256, 0, stream>>>(comps, bases, wtT);
        k_fused<<<GEMM_BLOCKS + COUNT_BLOCKS, 256, 0, stream>>>(nodes, wtT, nw, src, rel, cnt);
        k_scan1<<<NB_SCAN, 1024, 0, stream>>>(cnt, base2, bsums);
        k_scan2<<<1, 1024, 0, stream>>>(bsums, bsofs, NB_SCAN);
        k_scan3<<<(NM + 255) / 256, 256, 0, stream>>>(base2, bsofs);
        k_place<<<(EE + 255) / 256, 256, 0, stream>>>(src, rel, dst, base2, cnt, recs);
        k_accum<<<(NN + 3) / 4, 256, 0, stream>>>(base2, recs, nw, bias, out);
    } else {
        // fallback: counts f32 @0 (3.2MB), wtT @3,200,000
        float* countsF = (float*)ws;
        __hip_bfloat16* wtT2 = (__hip_bfloat16*)(ws + 3200000);
        k_zero<<<(NM + 255) / 256, 256, 0, stream>>>((int*)ws, NM);
        k_count_only<<<(EE + 255) / 256, 256, 0, stream>>>(src, rel, countsF);
        k_weights<<<(RR * H1 * H0 + 255) / 256, 256, 0, stream>>>(comps, bases, wtT2);
        k_init_out<<<(NN * H1 + 255) / 256, 256, 0, stream>>>(out, bias);
        k_fused_edge<<<EE / 4, 256, 0, stream>>>(src, rel, dst, nodes, countsF, wtT2, out);
    }
}

// Round 5
// 185.230 us; speedup vs baseline: 2.2871x; 1.1210x over previous
//
#include <hip/hip_runtime.h>
#include <hip/hip_bf16.h>

#define NN 50000
#define RR 16
#define H0 128
#define H1 64
#define EE 800000
#define NBASE 8
#define NTILES (NN / 16)            // 3125
#define NGRPS ((NTILES + 3) / 4)    // 782 groups of 64 nodes
#define GEMM_BLOCKS NGRPS
#define COUNT_BLOCKS ((EE + 255) / 256)  // 3125
#define NM (NN * RR)                // 800000 bins

typedef __attribute__((ext_vector_type(8))) short short8;
typedef __attribute__((ext_vector_type(4))) float f32x4;

__device__ inline short f2bs(float x) {
    __hip_bfloat16 b = __float2bfloat16(x);
    return *reinterpret_cast<short*>(&b);
}

// ---------------- weights = comps @ bases, bf16 transposed [r][o][k] ----------------
__global__ void k_weights(const float* __restrict__ comps, const float* __restrict__ bases,
                          __hip_bfloat16* __restrict__ wtT) {
    int idx = blockIdx.x * blockDim.x + threadIdx.x;
    if (idx >= RR * H1 * H0) return;
    int r = idx / (H1 * H0);
    int rem = idx % (H1 * H0);
    int o = rem / H0;
    int i = rem % H0;
    float acc = 0.0f;
#pragma unroll
    for (int b = 0; b < NBASE; ++b)
        acc += comps[r * NBASE + b] * bases[(b * H0 + i) * H1 + o];
    wtT[idx] = __float2bfloat16(acc);
}

// ---------------- fused: [gemm blocks] + [count blocks] ----------------
// gemm: wave owns 64 nodes x 4 rels. Channel-permuted B tiles (tile ot covers
// ch = (row>>2)*16 + ot*4 + (row&3)) so each lane accumulates 16 CONTIGUOUS
// channels [kg*16,kg*16+16). Packed bf16 staged via wave-private LDS (XOR
// swizzle), then 1KB fully-coalesced stores (8 full 128B rows per instr) --
// the store shape that measured zero write amplification in R2.
__global__ void k_fused(const float* __restrict__ nodes,
                        const __hip_bfloat16* __restrict__ wtT,
                        __hip_bfloat16* __restrict__ nw,
                        const int* __restrict__ src, const int* __restrict__ rel,
                        int* __restrict__ cnt) {
    __shared__ unsigned ldsu[4][2048];          // 8KB per wave, wave-private
    if (blockIdx.x < GEMM_BLOCKS) {
        int wid  = threadIdx.x >> 6;
        int lane = threadIdx.x & 63;
        int gw   = blockIdx.x * 4 + wid;
        int ngrp = gw >> 2;                      // 64-node group
        int rg   = gw & 3;                       // relation group
        int n16  = lane & 15;
        int kg   = lane >> 4;
        char* ldsb = (char*)&ldsu[wid][0];

        int ntl = NTILES - ngrp * 4;
        if (ntl > 4) ntl = 4;

        // A fragments: 4 tiles x 4 k-steps, f32->bf16 fused (64 VGPRs)
        short8 afrag[4][4];
#pragma unroll
        for (int t = 0; t < 4; ++t) {
            if (t < ntl) {
                const float* ap = &nodes[(size_t)((ngrp * 4 + t) * 16 + n16) * H0 + kg * 8];
#pragma unroll
                for (int ks = 0; ks < 4; ++ks) {
                    float4 lo = *(const float4*)(ap + ks * 32);
                    float4 hi = *(const float4*)(ap + ks * 32 + 4);
                    short8 a;
                    a[0] = f2bs(lo.x); a[1] = f2bs(lo.y); a[2] = f2bs(lo.z); a[3] = f2bs(lo.w);
                    a[4] = f2bs(hi.x); a[5] = f2bs(hi.y); a[6] = f2bs(hi.z); a[7] = f2bs(hi.w);
                    afrag[t][ks] = a;
                }
            }
        }

        int chb = (n16 >> 2) * 16 + (n16 & 3);   // permuted channel base for A-row n16

        for (int r0 = 0; r0 < 4; ++r0) {
            int r = rg * 4 + r0;
            const __hip_bfloat16* wrr = &wtT[((size_t)r * H1 + chb) * H0 + kg * 8];
            f32x4 acc[4][4];                     // [ot][tile]
#pragma unroll
            for (int ot = 0; ot < 4; ++ot)
#pragma unroll
                for (int t = 0; t < 4; ++t) acc[ot][t] = (f32x4){0, 0, 0, 0};

#pragma unroll
            for (int ot = 0; ot < 4; ++ot) {
#pragma unroll
                for (int ks = 0; ks < 4; ++ks) {
                    short8 w = *(const short8*)(wrr + (size_t)(ot * 4) * H0 + ks * 32);
                    acc[ot][0] = __builtin_amdgcn_mfma_f32_16x16x32_bf16(w, afrag[0][ks], acc[ot][0], 0, 0, 0);
                    acc[ot][1] = __builtin_amdgcn_mfma_f32_16x16x32_bf16(w, afrag[1][ks], acc[ot][1], 0, 0, 0);
                    acc[ot][2] = __builtin_amdgcn_mfma_f32_16x16x32_bf16(w, afrag[2][ks], acc[ot][2], 0, 0, 0);
                    acc[ot][3] = __builtin_amdgcn_mfma_f32_16x16x32_bf16(w, afrag[3][ks], acc[ot][3], 0, 0, 0);
                }
            }

            // stage: lane holds ch [kg*16, kg*16+16) of node (t,n16); ch = kg*16+ot*4+t
#pragma unroll
            for (int t = 0; t < 4; ++t) {
                if (t >= ntl) break;
                unsigned pk[8];
#pragma unroll
                for (int j = 0; j < 8; ++j) {    // u32 j = channels kg*16+2j, +1
                    f32x4 a = acc[j >> 1][t];
                    float lo = a[(j & 1) * 2], hi = a[(j & 1) * 2 + 1];
                    pk[j] = (unsigned)(unsigned short)f2bs(lo) |
                            ((unsigned)(unsigned short)f2bs(hi) << 16);
                }
                int node_l = t * 16 + n16;
                int off = node_l * 128 + ((kg ^ (n16 & 3)) << 5);   // XOR-swizzled 32B block
                uint4 q0; q0.x = pk[0]; q0.y = pk[1]; q0.z = pk[2]; q0.w = pk[3];
                uint4 q1; q1.x = pk[4]; q1.y = pk[5]; q1.z = pk[6]; q1.w = pk[7];
                *(uint4*)(ldsb + off)      = q0;
                *(uint4*)(ldsb + off + 16) = q1;
            }
            // drain: 8 x 1KB stores, each covering 8 FULL 128B rows
#pragma unroll
            for (int c = 0; c < 8; ++c) {
                int node_l = c * 8 + (lane >> 3);
                if (node_l < ntl * 16) {
                    int blk = (lane & 7) >> 1;
                    int roff = node_l * 128 + ((blk ^ (node_l & 3)) << 5) + (lane & 1) * 16;
                    uint4 q = *(uint4*)(ldsb + roff);
                    size_t gaddr = ((size_t)r * NN + (size_t)ngrp * 64 + node_l) * 128
                                   + (size_t)(lane & 7) * 16;
                    *(uint4*)((char*)nw + gaddr) = q;
                }
            }
        }
    } else {
        int e = (blockIdx.x - GEMM_BLOCKS) * 256 + threadIdx.x;
        if (e < EE) atomicAdd(&cnt[src[e] * RR + rel[e]], 1);
    }
}

// ---------------- scan level 1: 1024 elems/block, 256 thr x int4 ----------------
__global__ void k_scan1(const int* __restrict__ cnt, int* __restrict__ base2,
                        int* __restrict__ bsums) {
    __shared__ int tmp[256];
    int tid = threadIdx.x;
    int g = blockIdx.x * 256 + tid;
    int4 v = {0, 0, 0, 0};
    if (g * 4 < NM) v = *(const int4*)&cnt[g * 4];   // NM % 4 == 0
    int s = v.x + v.y + v.z + v.w;
    tmp[tid] = s;
    __syncthreads();
    for (int off = 1; off < 256; off <<= 1) {
        int t = (tid >= off) ? tmp[tid - off] : 0;
        __syncthreads();
        tmp[tid] += t;
        __syncthreads();
    }
    int excl = tmp[tid] - s;
    if (tid == 255) bsums[blockIdx.x] = tmp[255];
    if (g * 4 < NM) {
        int4 o;
        o.x = excl;
        o.y = excl + v.x;
        o.z = excl + v.x + v.y;
        o.w = excl + v.x + v.y + v.z;
        *(int4*)&base2[g * 4] = o;
    }
}

__global__ void k_scan2(const int* __restrict__ bsums, int* __restrict__ bsofs, int nb) {
    __shared__ int tmp[1024];
    int tid = threadIdx.x;
    int v = (tid < nb) ? bsums[tid] : 0;
    tmp[tid] = v;
    __syncthreads();
    for (int off = 1; off < 1024; off <<= 1) {
        int t = (tid >= off) ? tmp[tid - off] : 0;
        __syncthreads();
        tmp[tid] += t;
        __syncthreads();
    }
    if (tid < nb) bsofs[tid] = tmp[tid] - v;
}

__global__ void k_scan3(int* __restrict__ base2, const int* __restrict__ bsofs) {
    int g = blockIdx.x * blockDim.x + threadIdx.x;
    if (g * 4 < NM) {
        int ofs = bsofs[(g * 4) >> 10];
        int4 v = *(int4*)&base2[g * 4];
        v.x += ofs; v.y += ofs; v.z += ofs; v.w += ofs;
        *(int4*)&base2[g * 4] = v;
    }
    if (g == 0) base2[NM] = EE;
}

// ---------------- bucket-place edges; cnt reused as down-cursor ----------------
__global__ void k_place(const int* __restrict__ src, const int* __restrict__ rel,
                        const int* __restrict__ dst, const int* __restrict__ base2,
                        int* __restrict__ cnt, unsigned* __restrict__ recs) {
    int e = blockIdx.x * blockDim.x + threadIdx.x;
    if (e < EE) {
        int s = src[e], r = rel[e];
        int bin = s * RR + r;
        int old = atomicAdd(&cnt[bin], -1);
        int pos = base2[bin] + old - 1;
        recs[pos] = ((unsigned)r << 16) | (unsigned)dst[e];
    }
}

// ---------------- per-src accumulation: one wave per src, zero atomics ----------------
__global__ void k_accum(const int* __restrict__ base2, const unsigned* __restrict__ recs,
                        const __hip_bfloat16* __restrict__ nw, const float* __restrict__ bias,
                        float* __restrict__ out) {
    int s = blockIdx.x * 4 + (threadIdx.x >> 6);
    int lane = threadIdx.x & 63;
    if (s >= NN) return;
    int b0 = base2[s * RR];
    int n  = base2[s * RR + RR] - b0;
    const int* bnd = &base2[s * RR];
    float a0 = bias[lane], a1 = 0.0f, a2 = 0.0f, a3 = 0.0f;
    int i = 0;
    for (; i + 4 <= n; i += 4) {
        unsigned rec0 = recs[b0 + i], rec1 = recs[b0 + i + 1];
        unsigned rec2 = recs[b0 + i + 2], rec3 = recs[b0 + i + 3];
        int r0 = rec0 >> 16, d0 = rec0 & 0xFFFF;
        int r1 = rec1 >> 16, d1 = rec1 & 0xFFFF;
        int r2 = rec2 >> 16, d2 = rec2 & 0xFFFF;
        int r3 = rec3 >> 16, d3 = rec3 & 0xFFFF;
        float v0 = 1.0f / (float)(bnd[r0 + 1] - bnd[r0]);
        float v1 = 1.0f / (float)(bnd[r1 + 1] - bnd[r1]);
        float v2 = 1.0f / (float)(bnd[r2 + 1] - bnd[r2]);
        float v3 = 1.0f / (float)(bnd[r3 + 1] - bnd[r3]);
        float m0 = __bfloat162float(nw[((size_t)r0 * NN + d0) * H1 + lane]);
        float m1 = __bfloat162float(nw[((size_t)r1 * NN + d1) * H1 + lane]);
        float m2 = __bfloat162float(nw[((size_t)r2 * NN + d2) * H1 + lane]);
        float m3 = __bfloat162float(nw[((size_t)r3 * NN + d3) * H1 + lane]);
        a0 += v0 * m0; a1 += v1 * m1; a2 += v2 * m2; a3 += v3 * m3;
    }
    for (; i < n; ++i) {
        unsigned rec = recs[b0 + i];
        int r = rec >> 16, d = rec & 0xFFFF;
        a0 += (1.0f / (float)(bnd[r + 1] - bnd[r])) *
              __bfloat162float(nw[((size_t)r * NN + d) * H1 + lane]);
    }
    out[(size_t)s * H1 + lane] = (a0 + a1) + (a2 + a3);
}

// ---------------- fallback (small ws) ----------------
__global__ void k_init_out(float* __restrict__ out, const float* __restrict__ bias) {
    int i = blockIdx.x * blockDim.x + threadIdx.x;
    if (i < NN * H1) out[i] = bias[i & (H1 - 1)];
}

__global__ void k_count_only(const int* __restrict__ src, const int* __restrict__ rel,
                             float* __restrict__ counts) {
    int e = blockIdx.x * blockDim.x + threadIdx.x;
    if (e < EE) atomicAdd(&counts[rel[e] * NN + src[e]], 1.0f);
}

__global__ void k_fused_edge(const int* __restrict__ src, const int* __restrict__ rel,
                             const int* __restrict__ dst, const float* __restrict__ nodes,
                             const float* __restrict__ counts,
                             const __hip_bfloat16* __restrict__ wtT, float* __restrict__ out) {
    int e = blockIdx.x * (blockDim.x >> 6) + (threadIdx.x >> 6);
    int lane = threadIdx.x & 63;
    if (e >= EE) return;
    int s = src[e], r = rel[e], d = dst[e];
    float val = 1.0f / counts[r * NN + s];
    const __hip_bfloat16* w = &wtT[(size_t)(r * H1 + lane) * H0];
    const float* nd = &nodes[(size_t)d * H0];
    float acc = 0.0f;
#pragma unroll 8
    for (int i = 0; i < H0; ++i) acc += nd[i] * __bfloat162float(w[i]);
    atomicAdd(&out[s * H1 + lane], acc * val);
}

extern "C" void kernel_launch(void* const* d_in, const int* in_sizes, int n_in,
                              void* d_out, int out_size, void* d_ws, size_t ws_size,
                              hipStream_t stream) {
    const float* nodes = (const float*)d_in[0];
    const float* comps = (const float*)d_in[1];
    const float* bases = (const float*)d_in[2];
    const float* bias  = (const float*)d_in[3];
    const int*   src   = (const int*)d_in[4];
    const int*   rel   = (const int*)d_in[5];
    const int*   dst   = (const int*)d_in[6];
    float* out = (float*)d_out;

    char* ws = (char*)d_ws;
    // ws layout (bytes):
    //   cnt    i32 [NM]       @ 0           (3,200,000)
    //   base2  i32 [NM+1]     @ 3,200,000   (3,200,016)
    //   bsums  i32 [800]      @ 6,400,016
    //   bsofs  i32 [800]      @ 6,403,216
    //   wtT    bf16 [R*H1*H0] @ 6,406,416   (262,144)
    //   recs   u32 [EE]       @ 6,668,560   (3,200,000)
    //   nw     bf16 [R*N*H1]  @ 9,868,560   (102,400,000) -> total 112,268,560
    int*   cnt           = (int*)ws;
    int*   base2         = (int*)(ws + 3200000);
    int*   bsums         = (int*)(ws + 6400016);
    int*   bsofs         = (int*)(ws + 6403216);
    __hip_bfloat16* wtT  = (__hip_bfloat16*)(ws + 6406416);
    unsigned* recs       = (unsigned*)(ws + 6668560);
    __hip_bfloat16* nw   = (__hip_bfloat16*)(ws + 9868560);
    const size_t need_full = 9868560ull + (size_t)RR * NN * H1 * 2ull;

    if (ws_size >= need_full) {
        const int NB_SCAN = (NM + 1023) / 1024;   // 782
        hipMemsetAsync(cnt, 0, (size_t)NM * 4, stream);
        k_weights<<<(RR * H1 * H0 + 255) / 256, 256, 0, stream>>>(comps, bases, wtT);
        k_fused<<<GEMM_BLOCKS + COUNT_BLOCKS, 256, 0, stream>>>(nodes, wtT, nw, src, rel, cnt);
        k_scan1<<<NB_SCAN, 256, 0, stream>>>(cnt, base2, bsums);
        k_scan2<<<1, 1024, 0, stream>>>(bsums, bsofs, NB_SCAN);
        k_scan3<<<(NM / 4 + 255) / 256, 256, 0, stream>>>(base2, bsofs);
        k_place<<<(EE + 255) / 256, 256, 0, stream>>>(src, rel, dst, base2, cnt, recs);
        k_accum<<<(NN + 3) / 4, 256, 0, stream>>>(base2, recs, nw, bias, out);
    } else {
        float* countsF = (float*)ws;
        __hip_bfloat16* wtT2 = (__hip_bfloat16*)(ws + 3200000);
        hipMemsetAsync(countsF, 0, (size_t)NM * 4, stream);
        k_count_only<<<(EE + 255) / 256, 256, 0, stream>>>(src, rel, countsF);
        k_weights<<<(RR * H1 * H0 + 255) / 256, 256, 0, stream>>>(comps, bases, wtT2);
        k_init_out<<<(NN * H1 + 255) / 256, 256, 0, stream>>>(out, bias);
        k_fused_edge<<<EE / 4, 256, 0, stream>>>(src, rel, dst, nodes, countsF, wtT2, out);
    }
}

// Round 6
// 158.540 us; speedup vs baseline: 2.6722x; 1.1683x over previous
//
#include <hip/hip_runtime.h>
#include <hip/hip_bf16.h>

#define NN 50000
#define RR 16
#define H0 128
#define H1 64
#define EE 800000
#define NBASE 8
#define NTILES (NN / 16)            // 3125
#define NGRPS ((NTILES + 3) / 4)    // 782 groups of 64 nodes
#define GEMM_BLOCKS NGRPS
#define COUNT_BLOCKS ((EE + 255) / 256)  // 3125
#define NM (NN * RR)                // 800000 bins

typedef __attribute__((ext_vector_type(8))) short short8;
typedef __attribute__((ext_vector_type(4))) float f32x4;

__device__ inline short f2bs(float x) {
    __hip_bfloat16 b = __float2bfloat16(x);
    return *reinterpret_cast<short*>(&b);
}

// ---------------- weights = comps @ bases, bf16 transposed [r][o][k] ----------------
__global__ void k_weights(const float* __restrict__ comps, const float* __restrict__ bases,
                          __hip_bfloat16* __restrict__ wtT) {
    int idx = blockIdx.x * blockDim.x + threadIdx.x;
    if (idx >= RR * H1 * H0) return;
    int r = idx / (H1 * H0);
    int rem = idx % (H1 * H0);
    int o = rem / H0;
    int i = rem % H0;
    float acc = 0.0f;
#pragma unroll
    for (int b = 0; b < NBASE; ++b)
        acc += comps[r * NBASE + b] * bases[(b * H0 + i) * H1 + o];
    wtT[idx] = __float2bfloat16(acc);
}

// ---------------- fused: [gemm blocks] + [count+rank blocks] ----------------
// gemm: wave owns 64 nodes x 4 rels, channel-permuted B tiles so each lane
// accumulates 16 CONTIGUOUS channels [kg*16,kg*16+16) of one node = 32B,
// stored directly as two adjacent uint4 (no LDS roundtrip).
// count: rank[e] = atomicAdd(cnt[s*16+r], 1)  -- returning atomic; k_place
// then needs no atomics at all.
__global__ void k_fused(const float* __restrict__ nodes,
                        const __hip_bfloat16* __restrict__ wtT,
                        __hip_bfloat16* __restrict__ nw,
                        const int* __restrict__ src, const int* __restrict__ rel,
                        int* __restrict__ cnt, int* __restrict__ rank) {
    if (blockIdx.x < GEMM_BLOCKS) {
        int wid  = threadIdx.x >> 6;
        int lane = threadIdx.x & 63;
        int gw   = blockIdx.x * 4 + wid;
        int ngrp = gw >> 2;                      // 64-node group
        int rg   = gw & 3;                       // relation group
        int n16  = lane & 15;
        int kg   = lane >> 4;

        int ntl = NTILES - ngrp * 4;
        if (ntl > 4) ntl = 4;

        // A fragments: 4 tiles x 4 k-steps, f32->bf16 fused (64 VGPRs)
        short8 afrag[4][4];
#pragma unroll
        for (int t = 0; t < 4; ++t) {
            if (t < ntl) {
                const float* ap = &nodes[(size_t)((ngrp * 4 + t) * 16 + n16) * H0 + kg * 8];
#pragma unroll
                for (int ks = 0; ks < 4; ++ks) {
                    float4 lo = *(const float4*)(ap + ks * 32);
                    float4 hi = *(const float4*)(ap + ks * 32 + 4);
                    short8 a;
                    a[0] = f2bs(lo.x); a[1] = f2bs(lo.y); a[2] = f2bs(lo.z); a[3] = f2bs(lo.w);
                    a[4] = f2bs(hi.x); a[5] = f2bs(hi.y); a[6] = f2bs(hi.z); a[7] = f2bs(hi.w);
                    afrag[t][ks] = a;
                }
            }
        }

        int chb = (n16 >> 2) * 16 + (n16 & 3);   // permuted channel base for A-row n16

        for (int r0 = 0; r0 < 4; ++r0) {
            int r = rg * 4 + r0;
            const __hip_bfloat16* wrr = &wtT[((size_t)r * H1 + chb) * H0 + kg * 8];
            f32x4 acc[4][4];                     // [ot][tile]
#pragma unroll
            for (int ot = 0; ot < 4; ++ot)
#pragma unroll
                for (int t = 0; t < 4; ++t) acc[ot][t] = (f32x4){0, 0, 0, 0};

#pragma unroll
            for (int ot = 0; ot < 4; ++ot) {
#pragma unroll
                for (int ks = 0; ks < 4; ++ks) {
                    short8 w = *(const short8*)(wrr + (size_t)(ot * 4) * H0 + ks * 32);
                    acc[ot][0] = __builtin_amdgcn_mfma_f32_16x16x32_bf16(w, afrag[0][ks], acc[ot][0], 0, 0, 0);
                    acc[ot][1] = __builtin_amdgcn_mfma_f32_16x16x32_bf16(w, afrag[1][ks], acc[ot][1], 0, 0, 0);
                    acc[ot][2] = __builtin_amdgcn_mfma_f32_16x16x32_bf16(w, afrag[2][ks], acc[ot][2], 0, 0, 0);
                    acc[ot][3] = __builtin_amdgcn_mfma_f32_16x16x32_bf16(w, afrag[3][ks], acc[ot][3], 0, 0, 0);
                }
            }

            // lane holds channels kg*16+ot*4+treg of node (t,n16); pack to
            // 32 contiguous bytes and store directly (2 adjacent uint4).
#pragma unroll
            for (int t = 0; t < 4; ++t) {
                if (t >= ntl) break;
                unsigned pk[8];
#pragma unroll
                for (int j = 0; j < 8; ++j) {    // u32 j = channels kg*16+2j, +1
                    f32x4 a = acc[j >> 1][t];
                    float lo = a[(j & 1) * 2], hi = a[(j & 1) * 2 + 1];
                    pk[j] = (unsigned)(unsigned short)f2bs(lo) |
                            ((unsigned)(unsigned short)f2bs(hi) << 16);
                }
                uint4 q0; q0.x = pk[0]; q0.y = pk[1]; q0.z = pk[2]; q0.w = pk[3];
                uint4 q1; q1.x = pk[4]; q1.y = pk[5]; q1.z = pk[6]; q1.w = pk[7];
                char* gp = (char*)nw +
                           ((size_t)r * NN + (size_t)ngrp * 64 + t * 16 + n16) * 128 + kg * 32;
                *(uint4*)gp        = q0;
                *(uint4*)(gp + 16) = q1;
            }
        }
    } else {
        int e = (blockIdx.x - GEMM_BLOCKS) * 256 + threadIdx.x;
        if (e < EE) {
            int bin = src[e] * RR + rel[e];
            rank[e] = atomicAdd(&cnt[bin], 1);
        }
    }
}

// ---------------- scan level 1: 1024 elems/block, 256 thr x int4 ----------------
__global__ void k_scan1(const int* __restrict__ cnt, int* __restrict__ base2,
                        int* __restrict__ bsums) {
    __shared__ int tmp[256];
    int tid = threadIdx.x;
    int g = blockIdx.x * 256 + tid;
    int4 v = {0, 0, 0, 0};
    if (g * 4 < NM) v = *(const int4*)&cnt[g * 4];   // NM % 4 == 0
    int s = v.x + v.y + v.z + v.w;
    tmp[tid] = s;
    __syncthreads();
    for (int off = 1; off < 256; off <<= 1) {
        int t = (tid >= off) ? tmp[tid - off] : 0;
        __syncthreads();
        tmp[tid] += t;
        __syncthreads();
    }
    int excl = tmp[tid] - s;
    if (tid == 255) bsums[blockIdx.x] = tmp[255];
    if (g * 4 < NM) {
        int4 o;
        o.x = excl;
        o.y = excl + v.x;
        o.z = excl + v.x + v.y;
        o.w = excl + v.x + v.y + v.z;
        *(int4*)&base2[g * 4] = o;
    }
}

__global__ void k_scan2(const int* __restrict__ bsums, int* __restrict__ bsofs, int nb) {
    __shared__ int tmp[1024];
    int tid = threadIdx.x;
    int v = (tid < nb) ? bsums[tid] : 0;
    tmp[tid] = v;
    __syncthreads();
    for (int off = 1; off < 1024; off <<= 1) {
        int t = (tid >= off) ? tmp[tid - off] : 0;
        __syncthreads();
        tmp[tid] += t;
        __syncthreads();
    }
    if (tid < nb) bsofs[tid] = tmp[tid] - v;
}

__global__ void k_scan3(int* __restrict__ base2, const int* __restrict__ bsofs) {
    int g = blockIdx.x * blockDim.x + threadIdx.x;
    if (g * 4 < NM) {
        int ofs = bsofs[(g * 4) >> 10];
        int4 v = *(int4*)&base2[g * 4];
        v.x += ofs; v.y += ofs; v.z += ofs; v.w += ofs;
        *(int4*)&base2[g * 4] = v;
    }
    if (g == 0) base2[NM] = EE;
}

// ---------------- place edges, NO atomics: pos = base2[bin] + rank[e] ----------------
__global__ void k_place(const int* __restrict__ src, const int* __restrict__ rel,
                        const int* __restrict__ dst, const int* __restrict__ base2,
                        const int* __restrict__ rank, unsigned* __restrict__ recs) {
    int e = blockIdx.x * blockDim.x + threadIdx.x;
    if (e < EE) {
        int s = src[e], r = rel[e];
        int pos = base2[s * RR + r] + rank[e];
        recs[pos] = ((unsigned)r << 16) | (unsigned)dst[e];
    }
}

// ---------------- per-src accumulation: one wave per src, zero atomics ----------------
__global__ void k_accum(const int* __restrict__ base2, const unsigned* __restrict__ recs,
                        const __hip_bfloat16* __restrict__ nw, const float* __restrict__ bias,
                        float* __restrict__ out) {
    int s = blockIdx.x * 4 + (threadIdx.x >> 6);
    int lane = threadIdx.x & 63;
    if (s >= NN) return;
    int b0 = base2[s * RR];
    int n  = base2[s * RR + RR] - b0;
    const int* bnd = &base2[s * RR];
    float a0 = bias[lane], a1 = 0.0f, a2 = 0.0f, a3 = 0.0f;
    int i = 0;
    for (; i + 4 <= n; i += 4) {
        unsigned rec0 = recs[b0 + i], rec1 = recs[b0 + i + 1];
        unsigned rec2 = recs[b0 + i + 2], rec3 = recs[b0 + i + 3];
        int r0 = rec0 >> 16, d0 = rec0 & 0xFFFF;
        int r1 = rec1 >> 16, d1 = rec1 & 0xFFFF;
        int r2 = rec2 >> 16, d2 = rec2 & 0xFFFF;
        int r3 = rec3 >> 16, d3 = rec3 & 0xFFFF;
        float v0 = 1.0f / (float)(bnd[r0 + 1] - bnd[r0]);
        float v1 = 1.0f / (float)(bnd[r1 + 1] - bnd[r1]);
        float v2 = 1.0f / (float)(bnd[r2 + 1] - bnd[r2]);
        float v3 = 1.0f / (float)(bnd[r3 + 1] - bnd[r3]);
        float m0 = __bfloat162float(nw[((size_t)r0 * NN + d0) * H1 + lane]);
        float m1 = __bfloat162float(nw[((size_t)r1 * NN + d1) * H1 + lane]);
        float m2 = __bfloat162float(nw[((size_t)r2 * NN + d2) * H1 + lane]);
        float m3 = __bfloat162float(nw[((size_t)r3 * NN + d3) * H1 + lane]);
        a0 += v0 * m0; a1 += v1 * m1; a2 += v2 * m2; a3 += v3 * m3;
    }
    for (; i < n; ++i) {
        unsigned rec = recs[b0 + i];
        int r = rec >> 16, d = rec & 0xFFFF;
        a0 += (1.0f / (float)(bnd[r + 1] - bnd[r])) *
              __bfloat162float(nw[((size_t)r * NN + d) * H1 + lane]);
    }
    out[(size_t)s * H1 + lane] = (a0 + a1) + (a2 + a3);
}

// ---------------- fallback (small ws) ----------------
__global__ void k_init_out(float* __restrict__ out, const float* __restrict__ bias) {
    int i = blockIdx.x * blockDim.x + threadIdx.x;
    if (i < NN * H1) out[i] = bias[i & (H1 - 1)];
}

__global__ void k_count_only(const int* __restrict__ src, const int* __restrict__ rel,
                             float* __restrict__ counts) {
    int e = blockIdx.x * blockDim.x + threadIdx.x;
    if (e < EE) atomicAdd(&counts[rel[e] * NN + src[e]], 1.0f);
}

__global__ void k_fused_edge(const int* __restrict__ src, const int* __restrict__ rel,
                             const int* __restrict__ dst, const float* __restrict__ nodes,
                             const float* __restrict__ counts,
                             const __hip_bfloat16* __restrict__ wtT, float* __restrict__ out) {
    int e = blockIdx.x * (blockDim.x >> 6) + (threadIdx.x >> 6);
    int lane = threadIdx.x & 63;
    if (e >= EE) return;
    int s = src[e], r = rel[e], d = dst[e];
    float val = 1.0f / counts[r * NN + s];
    const __hip_bfloat16* w = &wtT[(size_t)(r * H1 + lane) * H0];
    const float* nd = &nodes[(size_t)d * H0];
    float acc = 0.0f;
#pragma unroll 8
    for (int i = 0; i < H0; ++i) acc += nd[i] * __bfloat162float(w[i]);
    atomicAdd(&out[s * H1 + lane], acc * val);
}

extern "C" void kernel_launch(void* const* d_in, const int* in_sizes, int n_in,
                              void* d_out, int out_size, void* d_ws, size_t ws_size,
                              hipStream_t stream) {
    const float* nodes = (const float*)d_in[0];
    const float* comps = (const float*)d_in[1];
    const float* bases = (const float*)d_in[2];
    const float* bias  = (const float*)d_in[3];
    const int*   src   = (const int*)d_in[4];
    const int*   rel   = (const int*)d_in[5];
    const int*   dst   = (const int*)d_in[6];
    float* out = (float*)d_out;

    char* ws = (char*)d_ws;
    // ws layout (bytes), all 256-aligned, nw 128-aligned:
    //   cnt    i32 [NM]       @ 0           (3,200,000)
    //   base2  i32 [NM+1]     @ 3,200,256   (3,200,016)
    //   bsums  i32 [800]      @ 6,400,512
    //   bsofs  i32 [800]      @ 6,403,968
    //   wtT    bf16 [R*H1*H0] @ 6,407,424   (262,144)
    //   rank   i32 [EE]       @ 6,669,824   (3,200,000)
    //   recs   u32 [EE]       @ 9,870,080   (3,200,000)
    //   nw     bf16 [R*N*H1]  @ 13,070,080  (102,400,000) -> total 115,470,080
    int*   cnt           = (int*)ws;
    int*   base2         = (int*)(ws + 3200256);
    int*   bsums         = (int*)(ws + 6400512);
    int*   bsofs         = (int*)(ws + 6403968);
    __hip_bfloat16* wtT  = (__hip_bfloat16*)(ws + 6407424);
    int*   rank          = (int*)(ws + 6669824);
    unsigned* recs       = (unsigned*)(ws + 9870080);
    __hip_bfloat16* nw   = (__hip_bfloat16*)(ws + 13070080);
    const size_t need_full = 13070080ull + (size_t)RR * NN * H1 * 2ull;

    if (ws_size >= need_full) {
        const int NB_SCAN = (NM + 1023) / 1024;   // 782
        hipMemsetAsync(cnt, 0, (size_t)NM * 4, stream);
        k_weights<<<(RR * H1 * H0 + 255) / 256, 256, 0, stream>>>(comps, bases, wtT);
        k_fused<<<GEMM_BLOCKS + COUNT_BLOCKS, 256, 0, stream>>>(nodes, wtT, nw, src, rel, cnt, rank);
        k_scan1<<<NB_SCAN, 256, 0, stream>>>(cnt, base2, bsums);
        k_scan2<<<1, 1024, 0, stream>>>(bsums, bsofs, NB_SCAN);
        k_scan3<<<(NM / 4 + 255) / 256, 256, 0, stream>>>(base2, bsofs);
        k_place<<<(EE + 255) / 256, 256, 0, stream>>>(src, rel, dst, base2, rank, recs);
        k_accum<<<(NN + 3) / 4, 256, 0, stream>>>(base2, recs, nw, bias, out);
    } else {
        float* countsF = (float*)ws;
        __hip_bfloat16* wtT2 = (__hip_bfloat16*)(ws + 3200256);
        hipMemsetAsync(countsF, 0, (size_t)NM * 4, stream);
        k_count_only<<<(EE + 255) / 256, 256, 0, stream>>>(src, rel, countsF);
        k_weights<<<(RR * H1 * H0 + 255) / 256, 256, 0, stream>>>(comps, bases, wtT2);
        k_init_out<<<(NN * H1 + 255) / 256, 256, 0, stream>>>(out, bias);
        k_fused_edge<<<EE / 4, 256, 0, stream>>>(src, rel, dst, nodes, countsF, wtT2, out);
    }
}

// Round 7
// 155.234 us; speedup vs baseline: 2.7291x; 1.0213x over previous
//
#include <hip/hip_runtime.h>
#include <hip/hip_bf16.h>

#define NN 50000
#define RR 16
#define H0 128
#define H1 64
#define EE 800000
#define NBASE 8
#define NTILES (NN / 16)            // 3125
#define NGRPS ((NTILES + 3) / 4)    // 782 groups of 64 nodes
#define GEMM_BLOCKS NGRPS
#define COUNT_BLOCKS ((EE + 255) / 256)  // 3125
#define NM (NN * RR)                // 800000 bins

typedef __attribute__((ext_vector_type(8))) short short8;
typedef __attribute__((ext_vector_type(4))) float f32x4;

__device__ inline short f2bs(float x) {
    __hip_bfloat16 b = __float2bfloat16(x);
    return *reinterpret_cast<short*>(&b);
}

// ---------------- weights = comps @ bases, bf16 transposed [r][o][k] ----------------
__global__ void k_weights(const float* __restrict__ comps, const float* __restrict__ bases,
                          __hip_bfloat16* __restrict__ wtT) {
    int idx = blockIdx.x * blockDim.x + threadIdx.x;
    if (idx >= RR * H1 * H0) return;
    int r = idx / (H1 * H0);
    int rem = idx % (H1 * H0);
    int o = rem / H0;
    int i = rem % H0;
    float acc = 0.0f;
#pragma unroll
    for (int b = 0; b < NBASE; ++b)
        acc += comps[r * NBASE + b] * bases[(b * H0 + i) * H1 + o];
    wtT[idx] = __float2bfloat16(acc);
}

// ---------------- fused: [gemm blocks] + [count+rank blocks] ----------------
// gemm: wave owns 64 nodes x 4 rels, channel-permuted B tiles; lane (n16,kg)
// accumulates channels [kg*16, kg*16+16) of node n16.
// nw row layout is PERMUTED so each store instruction covers complete 64B
// sectors: q0 -> row byte kg*16 (all 4 kg fill bytes [0,64) of the row),
// q1 -> row byte 64+kg*16. Element at index ((l>>3)&1)*32+(l>>4)*8+(l&7)
// holds channel l; k_accum reads with this static map.
// count: rank[e] = atomicAdd(cnt[s*16+r], 1); k_place then needs no atomics.
__global__ void k_fused(const float* __restrict__ nodes,
                        const __hip_bfloat16* __restrict__ wtT,
                        __hip_bfloat16* __restrict__ nw,
                        const int* __restrict__ src, const int* __restrict__ rel,
                        int* __restrict__ cnt, int* __restrict__ rank) {
    if (blockIdx.x < GEMM_BLOCKS) {
        int wid  = threadIdx.x >> 6;
        int lane = threadIdx.x & 63;
        int gw   = blockIdx.x * 4 + wid;
        int ngrp = gw >> 2;                      // 64-node group
        int rg   = gw & 3;                       // relation group
        int n16  = lane & 15;
        int kg   = lane >> 4;

        int ntl = NTILES - ngrp * 4;
        if (ntl > 4) ntl = 4;

        // A fragments: 4 tiles x 4 k-steps, f32->bf16 fused (64 VGPRs)
        short8 afrag[4][4];
#pragma unroll
        for (int t = 0; t < 4; ++t) {
            if (t < ntl) {
                const float* ap = &nodes[(size_t)((ngrp * 4 + t) * 16 + n16) * H0 + kg * 8];
#pragma unroll
                for (int ks = 0; ks < 4; ++ks) {
                    float4 lo = *(const float4*)(ap + ks * 32);
                    float4 hi = *(const float4*)(ap + ks * 32 + 4);
                    short8 a;
                    a[0] = f2bs(lo.x); a[1] = f2bs(lo.y); a[2] = f2bs(lo.z); a[3] = f2bs(lo.w);
                    a[4] = f2bs(hi.x); a[5] = f2bs(hi.y); a[6] = f2bs(hi.z); a[7] = f2bs(hi.w);
                    afrag[t][ks] = a;
                }
            }
        }

        int chb = (n16 >> 2) * 16 + (n16 & 3);   // permuted channel base for A-row n16

        for (int r0 = 0; r0 < 4; ++r0) {
            int r = rg * 4 + r0;
            const __hip_bfloat16* wrr = &wtT[((size_t)r * H1 + chb) * H0 + kg * 8];
            f32x4 acc[4][4];                     // [ot][tile]
#pragma unroll
            for (int ot = 0; ot < 4; ++ot)
#pragma unroll
                for (int t = 0; t < 4; ++t) acc[ot][t] = (f32x4){0, 0, 0, 0};

#pragma unroll
            for (int ot = 0; ot < 4; ++ot) {
#pragma unroll
                for (int ks = 0; ks < 4; ++ks) {
                    short8 w = *(const short8*)(wrr + (size_t)(ot * 4) * H0 + ks * 32);
                    acc[ot][0] = __builtin_amdgcn_mfma_f32_16x16x32_bf16(w, afrag[0][ks], acc[ot][0], 0, 0, 0);
                    acc[ot][1] = __builtin_amdgcn_mfma_f32_16x16x32_bf16(w, afrag[1][ks], acc[ot][1], 0, 0, 0);
                    acc[ot][2] = __builtin_amdgcn_mfma_f32_16x16x32_bf16(w, afrag[2][ks], acc[ot][2], 0, 0, 0);
                    acc[ot][3] = __builtin_amdgcn_mfma_f32_16x16x32_bf16(w, afrag[3][ks], acc[ot][3], 0, 0, 0);
                }
            }

            // lane holds channels kg*16 .. kg*16+15 of node (t,n16) in pk[0..7].
            // Sector-complete stores: q0 -> byte kg*16, q1 -> byte 64+kg*16.
#pragma unroll
            for (int t = 0; t < 4; ++t) {
                if (t >= ntl) break;
                unsigned pk[8];
#pragma unroll
                for (int j = 0; j < 8; ++j) {    // pk[j] = channels kg*16+2j, +1
                    f32x4 a = acc[j >> 1][t];
                    float lo = a[(j & 1) * 2], hi = a[(j & 1) * 2 + 1];
                    pk[j] = (unsigned)(unsigned short)f2bs(lo) |
                            ((unsigned)(unsigned short)f2bs(hi) << 16);
                }
                uint4 q0; q0.x = pk[0]; q0.y = pk[1]; q0.z = pk[2]; q0.w = pk[3];
                uint4 q1; q1.x = pk[4]; q1.y = pk[5]; q1.z = pk[6]; q1.w = pk[7];
                char* rowp = (char*)nw +
                             ((size_t)r * NN + (size_t)ngrp * 64 + t * 16 + n16) * 128;
                *(uint4*)(rowp + kg * 16)      = q0;   // bytes [0,64) of row
                *(uint4*)(rowp + 64 + kg * 16) = q1;   // bytes [64,128) of row
            }
        }
    } else {
        int e = (blockIdx.x - GEMM_BLOCKS) * 256 + threadIdx.x;
        if (e < EE) {
            int bin = src[e] * RR + rel[e];
            rank[e] = atomicAdd(&cnt[bin], 1);
        }
    }
}

// ---------------- scan level 1: 1024 elems/block, 256 thr x int4 ----------------
__global__ void k_scan1(const int* __restrict__ cnt, int* __restrict__ base2,
                        int* __restrict__ bsums) {
    __shared__ int tmp[256];
    int tid = threadIdx.x;
    int g = blockIdx.x * 256 + tid;
    int4 v = {0, 0, 0, 0};
    if (g * 4 < NM) v = *(const int4*)&cnt[g * 4];   // NM % 4 == 0
    int s = v.x + v.y + v.z + v.w;
    tmp[tid] = s;
    __syncthreads();
    for (int off = 1; off < 256; off <<= 1) {
        int t = (tid >= off) ? tmp[tid - off] : 0;
        __syncthreads();
        tmp[tid] += t;
        __syncthreads();
    }
    int excl = tmp[tid] - s;
    if (tid == 255) bsums[blockIdx.x] = tmp[255];
    if (g * 4 < NM) {
        int4 o;
        o.x = excl;
        o.y = excl + v.x;
        o.z = excl + v.x + v.y;
        o.w = excl + v.x + v.y + v.z;
        *(int4*)&base2[g * 4] = o;
    }
}

__global__ void k_scan2(const int* __restrict__ bsums, int* __restrict__ bsofs, int nb) {
    __shared__ int tmp[1024];
    int tid = threadIdx.x;
    int v = (tid < nb) ? bsums[tid] : 0;
    tmp[tid] = v;
    __syncthreads();
    for (int off = 1; off < 1024; off <<= 1) {
        int t = (tid >= off) ? tmp[tid - off] : 0;
        __syncthreads();
        tmp[tid] += t;
        __syncthreads();
    }
    if (tid < nb) bsofs[tid] = tmp[tid] - v;
}

__global__ void k_scan3(int* __restrict__ base2, const int* __restrict__ bsofs) {
    int g = blockIdx.x * blockDim.x + threadIdx.x;
    if (g * 4 < NM) {
        int ofs = bsofs[(g * 4) >> 10];
        int4 v = *(int4*)&base2[g * 4];
        v.x += ofs; v.y += ofs; v.z += ofs; v.w += ofs;
        *(int4*)&base2[g * 4] = v;
    }
    if (g == 0) base2[NM] = EE;
}

// ---------------- place edges, NO atomics: pos = base2[bin] + rank[e] ----------------
__global__ void k_place(const int* __restrict__ src, const int* __restrict__ rel,
                        const int* __restrict__ dst, const int* __restrict__ base2,
                        const int* __restrict__ rank, unsigned* __restrict__ recs) {
    int e = blockIdx.x * blockDim.x + threadIdx.x;
    if (e < EE) {
        int s = src[e], r = rel[e];
        int pos = base2[s * RR + r] + rank[e];
        recs[pos] = ((unsigned)r << 16) | (unsigned)dst[e];
    }
}

// ---------------- per-src accumulation: one wave per src, zero atomics ----------------
// nw rows are channel-permuted: element ((l>>3)&1)*32+(l>>4)*8+(l&7) = channel l.
__global__ void k_accum(const int* __restrict__ base2, const unsigned* __restrict__ recs,
                        const __hip_bfloat16* __restrict__ nw, const float* __restrict__ bias,
                        float* __restrict__ out) {
    int s = blockIdx.x * 4 + (threadIdx.x >> 6);
    int lane = threadIdx.x & 63;
    if (s >= NN) return;
    int pl = ((lane >> 3) & 1) * 32 + (lane >> 4) * 8 + (lane & 7);  // permuted elem idx
    int b0 = base2[s * RR];
    int n  = base2[s * RR + RR] - b0;
    const int* bnd = &base2[s * RR];
    float a0 = bias[lane], a1 = 0.0f, a2 = 0.0f, a3 = 0.0f;
    int i = 0;
    for (; i + 4 <= n; i += 4) {
        unsigned rec0 = recs[b0 + i], rec1 = recs[b0 + i + 1];
        unsigned rec2 = recs[b0 + i + 2], rec3 = recs[b0 + i + 3];
        int r0 = rec0 >> 16, d0 = rec0 & 0xFFFF;
        int r1 = rec1 >> 16, d1 = rec1 & 0xFFFF;
        int r2 = rec2 >> 16, d2 = rec2 & 0xFFFF;
        int r3 = rec3 >> 16, d3 = rec3 & 0xFFFF;
        float v0 = 1.0f / (float)(bnd[r0 + 1] - bnd[r0]);
        float v1 = 1.0f / (float)(bnd[r1 + 1] - bnd[r1]);
        float v2 = 1.0f / (float)(bnd[r2 + 1] - bnd[r2]);
        float v3 = 1.0f / (float)(bnd[r3 + 1] - bnd[r3]);
        float m0 = __bfloat162float(nw[((size_t)r0 * NN + d0) * H1 + pl]);
        float m1 = __bfloat162float(nw[((size_t)r1 * NN + d1) * H1 + pl]);
        float m2 = __bfloat162float(nw[((size_t)r2 * NN + d2) * H1 + pl]);
        float m3 = __bfloat162float(nw[((size_t)r3 * NN + d3) * H1 + pl]);
        a0 += v0 * m0; a1 += v1 * m1; a2 += v2 * m2; a3 += v3 * m3;
    }
    for (; i < n; ++i) {
        unsigned rec = recs[b0 + i];
        int r = rec >> 16, d = rec & 0xFFFF;
        a0 += (1.0f / (float)(bnd[r + 1] - bnd[r])) *
              __bfloat162float(nw[((size_t)r * NN + d) * H1 + pl]);
    }
    out[(size_t)s * H1 + lane] = (a0 + a1) + (a2 + a3);
}

// ---------------- fallback (small ws) ----------------
__global__ void k_init_out(float* __restrict__ out, const float* __restrict__ bias) {
    int i = blockIdx.x * blockDim.x + threadIdx.x;
    if (i < NN * H1) out[i] = bias[i & (H1 - 1)];
}

__global__ void k_count_only(const int* __restrict__ src, const int* __restrict__ rel,
                             float* __restrict__ counts) {
    int e = blockIdx.x * blockDim.x + threadIdx.x;
    if (e < EE) atomicAdd(&counts[rel[e] * NN + src[e]], 1.0f);
}

__global__ void k_fused_edge(const int* __restrict__ src, const int* __restrict__ rel,
                             const int* __restrict__ dst, const float* __restrict__ nodes,
                             const float* __restrict__ counts,
                             const __hip_bfloat16* __restrict__ wtT, float* __restrict__ out) {
    int e = blockIdx.x * (blockDim.x >> 6) + (threadIdx.x >> 6);
    int lane = threadIdx.x & 63;
    if (e >= EE) return;
    int s = src[e], r = rel[e], d = dst[e];
    float val = 1.0f / counts[r * NN + s];
    const __hip_bfloat16* w = &wtT[(size_t)(r * H1 + lane) * H0];
    const float* nd = &nodes[(size_t)d * H0];
    float acc = 0.0f;
#pragma unroll 8
    for (int i = 0; i < H0; ++i) acc += nd[i] * __bfloat162float(w[i]);
    atomicAdd(&out[s * H1 + lane], acc * val);
}

extern "C" void kernel_launch(void* const* d_in, const int* in_sizes, int n_in,
                              void* d_out, int out_size, void* d_ws, size_t ws_size,
                              hipStream_t stream) {
    const float* nodes = (const float*)d_in[0];
    const float* comps = (const float*)d_in[1];
    const float* bases = (const float*)d_in[2];
    const float* bias  = (const float*)d_in[3];
    const int*   src   = (const int*)d_in[4];
    const int*   rel   = (const int*)d_in[5];
    const int*   dst   = (const int*)d_in[6];
    float* out = (float*)d_out;

    char* ws = (char*)d_ws;
    // ws layout (bytes), all 256-aligned, nw 128-aligned:
    //   cnt    i32 [NM]       @ 0           (3,200,000)
    //   base2  i32 [NM+1]     @ 3,200,256   (3,200,016)
    //   bsums  i32 [800]      @ 6,400,512
    //   bsofs  i32 [800]      @ 6,403,968
    //   wtT    bf16 [R*H1*H0] @ 6,407,424   (262,144)
    //   rank   i32 [EE]       @ 6,669,824   (3,200,000)
    //   recs   u32 [EE]       @ 9,870,080   (3,200,000)
    //   nw     bf16 [R*N*H1]  @ 13,070,080  (102,400,000) -> total 115,470,080
    int*   cnt           = (int*)ws;
    int*   base2         = (int*)(ws + 3200256);
    int*   bsums         = (int*)(ws + 6400512);
    int*   bsofs         = (int*)(ws + 6403968);
    __hip_bfloat16* wtT  = (__hip_bfloat16*)(ws + 6407424);
    int*   rank          = (int*)(ws + 6669824);
    unsigned* recs       = (unsigned*)(ws + 9870080);
    __hip_bfloat16* nw   = (__hip_bfloat16*)(ws + 13070080);
    const size_t need_full = 13070080ull + (size_t)RR * NN * H1 * 2ull;

    if (ws_size >= need_full) {
        const int NB_SCAN = (NM + 1023) / 1024;   // 782
        hipMemsetAsync(cnt, 0, (size_t)NM * 4, stream);
        k_weights<<<(RR * H1 * H0 + 255) / 256, 256, 0, stream>>>(comps, bases, wtT);
        k_fused<<<GEMM_BLOCKS + COUNT_BLOCKS, 256, 0, stream>>>(nodes, wtT, nw, src, rel, cnt, rank);
        k_scan1<<<NB_SCAN, 256, 0, stream>>>(cnt, base2, bsums);
        k_scan2<<<1, 1024, 0, stream>>>(bsums, bsofs, NB_SCAN);
        k_scan3<<<(NM / 4 + 255) / 256, 256, 0, stream>>>(base2, bsofs);
        k_place<<<(EE + 255) / 256, 256, 0, stream>>>(src, rel, dst, base2, rank, recs);
        k_accum<<<(NN + 3) / 4, 256, 0, stream>>>(base2, recs, nw, bias, out);
    } else {
        float* countsF = (float*)ws;
        __hip_bfloat16* wtT2 = (__hip_bfloat16*)(ws + 3200256);
        hipMemsetAsync(countsF, 0, (size_t)NM * 4, stream);
        k_count_only<<<(EE + 255) / 256, 256, 0, stream>>>(src, rel, countsF);
        k_weights<<<(RR * H1 * H0 + 255) / 256, 256, 0, stream>>>(comps, bases, wtT2);
        k_init_out<<<(NN * H1 + 255) / 256, 256, 0, stream>>>(out, bias);
        k_fused_edge<<<EE / 4, 256, 0, stream>>>(src, rel, dst, nodes, countsF, wtT2, out);
    }
}